// Round 1
// baseline (787.126 us; speedup 1.0000x reference)
//
#include <hip/hip_runtime.h>
#include <hip/hip_bf16.h>

using f32x4  = __attribute__((ext_vector_type(4))) float;
using bf16x8 = __attribute__((ext_vector_type(8))) short;
using bf16x4 = __attribute__((ext_vector_type(4))) short;

#define MTOT   16384
#define DMODEL 512
#define DINNER 1024
#define SEQ    2048

__device__ __forceinline__ short f2b(float f){
  unsigned u = __builtin_bit_cast(unsigned, f);
  u = (u + 0x7FFFu + ((u >> 16) & 1u)) >> 16;   // RNE
  return (short)u;
}

// ---------------- mask layout detection (bool/u8 vs i32 vs f32 vs i64) ----------------
__global__ void detect_mask(const unsigned char* __restrict__ m, int* __restrict__ flag){
  __shared__ int sge2, soff, soff8;
  int tid = threadIdx.x;
  if (tid == 0){ sge2 = 0; soff = 0; soff8 = 0; }
  __syncthreads();
  int ge2 = 0, off = 0, off8 = 0;
  for (int i = tid; i < 16384; i += 256){
    unsigned char b = m[i];
    if (b >= 2) ge2++;
    if ((i & 3) && b) off++;
    if (((i & 7) == 4) && b) off8++;
  }
  atomicAdd(&sge2, ge2); atomicAdd(&soff, off); atomicAdd(&soff8, off8);
  __syncthreads();
  if (tid == 0){
    int f;
    if      (sge2 > 0) f = 2;   // float32 0.0/1.0
    else if (soff > 0) f = 1;   // bool / uint8
    else if (soff8 > 0) f = 0;  // int32
    else               f = 3;   // int64
    *flag = f;
  }
}

__device__ __forceinline__ bool mask_at(const void* mask, int flag, int m){
  if (flag == 1) return ((const unsigned char*)mask)[m] != 0;
  if (flag == 2) return ((const float*)mask)[m] != 0.0f;
  if (flag == 3) return ((const int*)mask)[2*m] != 0;
  return ((const int*)mask)[m] != 0;
}

// ---------------- f32 -> bf16 elementwise (frames) ----------------
__global__ void cvt_bf16(const float* __restrict__ in, short* __restrict__ out){
  int i = (blockIdx.x * 256 + threadIdx.x) * 4;
  float4 v = *(const float4*)(in + i);
  bf16x4 o; o[0] = f2b(v.x); o[1] = f2b(v.y); o[2] = f2b(v.z); o[3] = f2b(v.w);
  *(bf16x4*)(out + i) = o;
}

// ---------------- weight transpose+convert: f32 [R][C] -> bf16 [C][R] ----------------
__global__ void transpose_w(const float* __restrict__ in, short* __restrict__ out, int R, int C){
  in  += (size_t)blockIdx.z * R * C;
  out += (size_t)blockIdx.z * R * C;
  __shared__ float t[32][33];
  int tx = threadIdx.x, ty = threadIdx.y;
  int r0 = blockIdx.y * 32, c0 = blockIdx.x * 32;
  #pragma unroll
  for (int i = 0; i < 4; i++)
    t[ty + i*8][tx] = in[(size_t)(r0 + ty + i*8) * C + c0 + tx];
  __syncthreads();
  #pragma unroll
  for (int i = 0; i < 4; i++)
    out[(size_t)(c0 + ty + i*8) * R + r0 + tx] = f2b(t[tx][ty + i*8]);
}

// ---------------- LayerNorm: f32 x[row,512] -> bf16 out (wave per row) ----------------
__global__ __launch_bounds__(256) void ln_k(const float* __restrict__ x,
                                            const float* __restrict__ sc,
                                            const float* __restrict__ bi,
                                            short* __restrict__ out){
  int row  = blockIdx.x * 4 + (threadIdx.x >> 6);
  int lane = threadIdx.x & 63;
  const float* p = x + (size_t)row * DMODEL + lane * 8;
  float4 a = *(const float4*)p;
  float4 b = *(const float4*)(p + 4);
  float s = a.x+a.y+a.z+a.w + b.x+b.y+b.z+b.w;
  float q = a.x*a.x+a.y*a.y+a.z*a.z+a.w*a.w + b.x*b.x+b.y*b.y+b.z*b.z+b.w*b.w;
  #pragma unroll
  for (int o = 32; o >= 1; o >>= 1){ s += __shfl_xor(s, o); q += __shfl_xor(q, o); }
  float mu  = s * (1.0f/DMODEL);
  float var = q * (1.0f/DMODEL) - mu*mu;
  float rs  = rsqrtf(var + 1e-5f);
  int c = lane * 8;
  float vals[8] = {a.x,a.y,a.z,a.w,b.x,b.y,b.z,b.w};
  bf16x8 o8;
  #pragma unroll
  for (int e = 0; e < 8; e++) o8[e] = f2b((vals[e]-mu)*rs*sc[c+e] + bi[c+e]);
  *(bf16x8*)(out + (size_t)row * DMODEL + c) = o8;
}

// ---------------- MFMA GEMM, 128x128 tile, BK=32, 4 waves, fused epilogues ----------------
// MODE 0: x = A@B + bias + pos_emb          (out f32 xbuf)
// MODE 1: u = A@B0+bias0, g = A@B1+bias1, out = bf16(u*silu(g))  (out bf16 obuf)
// MODE 2: x = (x + A@B + bias) * decay      (f32 xbuf in-place)
// MODE 3: out = mask ? A@B + bias : 0       (f32 fout)
template<int MODE>
__global__ __launch_bounds__(256) void gemm_k(
    const short* __restrict__ A, const short* __restrict__ B0, const short* __restrict__ B1,
    const float* __restrict__ bias0, const float* __restrict__ bias1,
    const float* __restrict__ pos, float* __restrict__ xbuf, short* __restrict__ obuf,
    float* __restrict__ fout, const void* __restrict__ mask, const int* __restrict__ flagp,
    int K, int ldo)
{
  constexpr int BM = 128, BN = 128, BK = 32, LDL = BK + 8;
  __shared__ short lA[BM * LDL];
  __shared__ short lB[(MODE == 1 ? 2 : 1) * BN * LDL];
  short* lB2 = lB + BN * LDL;

  const int n0 = blockIdx.x * BN, m0 = blockIdx.y * BM;
  const int tid = threadIdx.x, lane = tid & 63, wid = tid >> 6;
  const int wr = wid >> 1, wc = wid & 1;

  f32x4 acc[4][4]; f32x4 acc2[4][4];
  const f32x4 zero = {0.f, 0.f, 0.f, 0.f};
  #pragma unroll
  for (int i = 0; i < 4; i++)
    #pragma unroll
    for (int j = 0; j < 4; j++){
      acc[i][j] = zero;
      if constexpr (MODE == 1) acc2[i][j] = zero;
    }

  const int r1 = tid >> 2;            // 0..63 (rows r1 and r1+64)
  const int k1 = (tid & 3) * 8;       // 0,8,16,24

  for (int kt = 0; kt < K; kt += BK){
    bf16x8 va1 = *(const bf16x8*)&A[(size_t)(m0 + r1)      * K + kt + k1];
    bf16x8 va2 = *(const bf16x8*)&A[(size_t)(m0 + r1 + 64) * K + kt + k1];
    bf16x8 vb1 = *(const bf16x8*)&B0[(size_t)(n0 + r1)      * K + kt + k1];
    bf16x8 vb2 = *(const bf16x8*)&B0[(size_t)(n0 + r1 + 64) * K + kt + k1];
    bf16x8 vg1, vg2;
    if constexpr (MODE == 1){
      vg1 = *(const bf16x8*)&B1[(size_t)(n0 + r1)      * K + kt + k1];
      vg2 = *(const bf16x8*)&B1[(size_t)(n0 + r1 + 64) * K + kt + k1];
    }
    __syncthreads();
    *(bf16x8*)&lA[r1 * LDL + k1]        = va1;
    *(bf16x8*)&lA[(r1 + 64) * LDL + k1] = va2;
    *(bf16x8*)&lB[r1 * LDL + k1]        = vb1;
    *(bf16x8*)&lB[(r1 + 64) * LDL + k1] = vb2;
    if constexpr (MODE == 1){
      *(bf16x8*)&lB2[r1 * LDL + k1]        = vg1;
      *(bf16x8*)&lB2[(r1 + 64) * LDL + k1] = vg2;
    }
    __syncthreads();

    const int ko = (lane >> 4) * 8;
    const int rA = wr * 64 + (lane & 15);
    const int rB = wc * 64 + (lane & 15);
    bf16x8 aF[4], bF[4];
    #pragma unroll
    for (int i = 0; i < 4; i++) aF[i] = *(const bf16x8*)&lA[(rA + i*16) * LDL + ko];
    #pragma unroll
    for (int j = 0; j < 4; j++) bF[j] = *(const bf16x8*)&lB[(rB + j*16) * LDL + ko];
    #pragma unroll
    for (int i = 0; i < 4; i++)
      #pragma unroll
      for (int j = 0; j < 4; j++)
        acc[i][j] = __builtin_amdgcn_mfma_f32_16x16x32_bf16(aF[i], bF[j], acc[i][j], 0, 0, 0);
    if constexpr (MODE == 1){
      bf16x8 gF[4];
      #pragma unroll
      for (int j = 0; j < 4; j++) gF[j] = *(const bf16x8*)&lB2[(rB + j*16) * LDL + ko];
      #pragma unroll
      for (int i = 0; i < 4; i++)
        #pragma unroll
        for (int j = 0; j < 4; j++)
          acc2[i][j] = __builtin_amdgcn_mfma_f32_16x16x32_bf16(aF[i], gF[j], acc2[i][j], 0, 0, 0);
    }
  }

  // epilogue: C/D layout col = lane&15, row = (lane>>4)*4 + reg
  const int col0 = n0 + wc * 64 + (lane & 15);
  const int row0 = m0 + wr * 64 + (lane >> 4) * 4;
  int flag = 0;
  if constexpr (MODE == 3) flag = *flagp;

  #pragma unroll
  for (int i = 0; i < 4; i++){
    #pragma unroll
    for (int r = 0; r < 4; r++){
      const int gm = row0 + i * 16 + r;
      #pragma unroll
      for (int j = 0; j < 4; j++){
        const int gn = col0 + j * 16;
        float v = acc[i][j][r];
        if constexpr (MODE == 0){
          xbuf[(size_t)gm * ldo + gn] = v + bias0[gn] + pos[(size_t)(gm & (SEQ-1)) * DMODEL + gn];
        } else if constexpr (MODE == 1){
          float u = v + bias0[gn];
          float g = acc2[i][j][r] + bias1[gn];
          float sg = g / (1.0f + expf(-g));
          obuf[(size_t)gm * ldo + gn] = f2b(u * sg);
        } else if constexpr (MODE == 2){
          int s = gm & (SEQ-1);
          float d = (((s + 1) % 10) == 0) ? 0.1f : 1.0f;
          float y = v + bias0[gn];
          xbuf[(size_t)gm * ldo + gn] = (xbuf[(size_t)gm * ldo + gn] + y) * d;
        } else {
          bool mk = mask_at(mask, flag, gm);
          fout[(size_t)gm * ldo + gn] = mk ? (v + bias0[gn]) : 0.0f;
        }
      }
    }
  }
}

extern "C" void kernel_launch(void* const* d_in, const int* in_sizes, int n_in,
                              void* d_out, int out_size, void* d_ws, size_t ws_size,
                              hipStream_t stream){
  const float* frames    = (const float*)d_in[0];
  const void*  mask      = d_in[1];
  const float* W_in_proj = (const float*)d_in[2];
  const float* b_in_proj = (const float*)d_in[3];
  const float* pos_emb   = (const float*)d_in[4];
  const float* ln_scale  = (const float*)d_in[5];
  const float* ln_bias   = (const float*)d_in[6];
  const float* W_in      = (const float*)d_in[7];
  const float* b_in      = (const float*)d_in[8];
  const float* W_out     = (const float*)d_in[9];
  const float* b_out     = (const float*)d_in[10];
  const float* fn_scale  = (const float*)d_in[11];
  const float* fn_bias   = (const float*)d_in[12];
  const float* W_frame   = (const float*)d_in[13];
  const float* b_frame   = (const float*)d_in[14];
  const float* W_sym     = (const float*)d_in[15];
  const float* b_sym     = (const float*)d_in[16];

  char* w = (char*)d_ws;
  int*   flag = (int*)w;
  float* xbuf = (float*)(w + 256);                                    // 16384*512 f32
  short* nbuf = (short*)(w + 256 + 33554432);                         // 16384*512 bf16
  short* abuf = (short*)(w + 256 + 33554432 + 16777216);              // 16384*1024 bf16
  short* frb  = (short*)(w + 256 + 33554432 + 16777216 + 33554432);   // 16384*128 bf16
  short* Wt0  = frb + (size_t)16384 * 128;   // [512][128]
  short* Wt1  = Wt0 + (size_t)512 * 128;     // 4x [2048][512]
  short* Wt2  = Wt1 + (size_t)4 * 2048 * 512;// 4x [512][1024]
  short* Wt3  = Wt2 + (size_t)4 * 512 * 1024;// [128][512]
  short* Wt4  = Wt3 + (size_t)128 * 512;     // [256][512]

  detect_mask<<<1, 256, 0, stream>>>((const unsigned char*)mask, flag);
  cvt_bf16<<<2048, 256, 0, stream>>>(frames, frb);
  transpose_w<<<dim3(16,  4, 1), dim3(32, 8), 0, stream>>>(W_in_proj, Wt0, 128, 512);
  transpose_w<<<dim3(64, 16, 4), dim3(32, 8), 0, stream>>>(W_in,      Wt1, 512, 2048);
  transpose_w<<<dim3(16, 32, 4), dim3(32, 8), 0, stream>>>(W_out,     Wt2, 1024, 512);
  transpose_w<<<dim3(4,  16, 1), dim3(32, 8), 0, stream>>>(W_frame,   Wt3, 512, 128);
  transpose_w<<<dim3(8,  16, 1), dim3(32, 8), 0, stream>>>(W_sym,     Wt4, 512, 256);

  gemm_k<0><<<dim3(4, 128), 256, 0, stream>>>(frb, Wt0, nullptr, b_in_proj, nullptr, pos_emb,
      xbuf, nullptr, nullptr, nullptr, nullptr, 128, 512);

  for (int l = 0; l < 4; l++){
    ln_k<<<4096, 256, 0, stream>>>(xbuf, ln_scale + l*512, ln_bias + l*512, nbuf);
    gemm_k<1><<<dim3(8, 128), 256, 0, stream>>>(nbuf,
        Wt1 + (size_t)l*2048*512, Wt1 + (size_t)l*2048*512 + (size_t)1024*512,
        b_in + l*2048, b_in + l*2048 + 1024, nullptr,
        nullptr, abuf, nullptr, nullptr, nullptr, 512, 1024);
    gemm_k<2><<<dim3(4, 128), 256, 0, stream>>>(abuf, Wt2 + (size_t)l*512*1024, nullptr,
        b_out + l*512, nullptr, nullptr, xbuf, nullptr, nullptr, nullptr, nullptr, 1024, 512);
  }

  ln_k<<<4096, 256, 0, stream>>>(xbuf, fn_scale, fn_bias, nbuf);
  gemm_k<3><<<dim3(1, 128), 256, 0, stream>>>(nbuf, Wt3, nullptr, b_frame, nullptr, nullptr,
      nullptr, nullptr, (float*)d_out, mask, flag, 512, 128);
  gemm_k<3><<<dim3(2, 128), 256, 0, stream>>>(nbuf, Wt4, nullptr, b_sym, nullptr, nullptr,
      nullptr, nullptr, (float*)d_out + (size_t)16384*128, mask, flag, 512, 256);
}

// Round 2
// 582.043 us; speedup vs baseline: 1.3523x; 1.3523x over previous
//
#include <hip/hip_runtime.h>
#include <hip/hip_bf16.h>

using f32x4  = __attribute__((ext_vector_type(4))) float;
using bf16x8 = __attribute__((ext_vector_type(8))) short;
using bf16x4 = __attribute__((ext_vector_type(4))) short;

#define MTOT   16384
#define DMODEL 512
#define DINNER 1024
#define SEQ    2048

__device__ __forceinline__ short f2b(float f){
  unsigned u = __builtin_bit_cast(unsigned, f);
  u = (u + 0x7FFFu + ((u >> 16) & 1u)) >> 16;   // RNE
  return (short)u;
}

__device__ __forceinline__ void gl_lds16(const short* g, short* l){
  __builtin_amdgcn_global_load_lds(
      (const __attribute__((address_space(1))) void*)g,
      (__attribute__((address_space(3))) void*)l, 16, 0, 0);
}

// ---------------- mask layout detection (bool/u8 vs i32 vs f32 vs i64) ----------------
__global__ void detect_mask(const unsigned char* __restrict__ m, int* __restrict__ flag){
  __shared__ int sge2, soff, soff8;
  int tid = threadIdx.x;
  if (tid == 0){ sge2 = 0; soff = 0; soff8 = 0; }
  __syncthreads();
  int ge2 = 0, off = 0, off8 = 0;
  for (int i = tid; i < 16384; i += 256){
    unsigned char b = m[i];
    if (b >= 2) ge2++;
    if ((i & 3) && b) off++;
    if (((i & 7) == 4) && b) off8++;
  }
  atomicAdd(&sge2, ge2); atomicAdd(&soff, off); atomicAdd(&soff8, off8);
  __syncthreads();
  if (tid == 0){
    int f;
    if      (sge2 > 0) f = 2;   // float32 0.0/1.0
    else if (soff > 0) f = 1;   // bool / uint8
    else if (soff8 > 0) f = 0;  // int32
    else               f = 3;   // int64
    *flag = f;
  }
}

__device__ __forceinline__ bool mask_at(const void* mask, int flag, int m){
  if (flag == 1) return ((const unsigned char*)mask)[m] != 0;
  if (flag == 2) return ((const float*)mask)[m] != 0.0f;
  if (flag == 3) return ((const int*)mask)[2*m] != 0;
  return ((const int*)mask)[m] != 0;
}

// ---------------- f32 -> bf16 elementwise (frames) ----------------
__global__ void cvt_bf16(const float* __restrict__ in, short* __restrict__ out){
  int i = (blockIdx.x * 256 + threadIdx.x) * 4;
  float4 v = *(const float4*)(in + i);
  bf16x4 o; o[0] = f2b(v.x); o[1] = f2b(v.y); o[2] = f2b(v.z); o[3] = f2b(v.w);
  *(bf16x4*)(out + i) = o;
}

// ---------------- weight transpose+convert: f32 [R][C] -> bf16 [C][R] ----------------
__global__ void transpose_w(const float* __restrict__ in, short* __restrict__ out, int R, int C){
  in  += (size_t)blockIdx.z * R * C;
  out += (size_t)blockIdx.z * R * C;
  __shared__ float t[32][33];
  int tx = threadIdx.x, ty = threadIdx.y;
  int r0 = blockIdx.y * 32, c0 = blockIdx.x * 32;
  #pragma unroll
  for (int i = 0; i < 4; i++)
    t[ty + i*8][tx] = in[(size_t)(r0 + ty + i*8) * C + c0 + tx];
  __syncthreads();
  #pragma unroll
  for (int i = 0; i < 4; i++)
    out[(size_t)(c0 + ty + i*8) * R + r0 + tx] = f2b(t[tx][ty + i*8]);
}

// ---------------- LayerNorm: f32 x[row,512] -> bf16 out (wave per row) ----------------
__global__ __launch_bounds__(256) void ln_k(const float* __restrict__ x,
                                            const float* __restrict__ sc,
                                            const float* __restrict__ bi,
                                            short* __restrict__ out){
  int row  = blockIdx.x * 4 + (threadIdx.x >> 6);
  int lane = threadIdx.x & 63;
  const float* p = x + (size_t)row * DMODEL + lane * 8;
  float4 a = *(const float4*)p;
  float4 b = *(const float4*)(p + 4);
  float s = a.x+a.y+a.z+a.w + b.x+b.y+b.z+b.w;
  float q = a.x*a.x+a.y*a.y+a.z*a.z+a.w*a.w + b.x*b.x+b.y*b.y+b.z*b.z+b.w*b.w;
  #pragma unroll
  for (int o = 32; o >= 1; o >>= 1){ s += __shfl_xor(s, o); q += __shfl_xor(q, o); }
  float mu  = s * (1.0f/DMODEL);
  float var = q * (1.0f/DMODEL) - mu*mu;
  float rs  = rsqrtf(var + 1e-5f);
  int c = lane * 8;
  float vals[8] = {a.x,a.y,a.z,a.w,b.x,b.y,b.z,b.w};
  bf16x8 o8;
  #pragma unroll
  for (int e = 0; e < 8; e++) o8[e] = f2b((vals[e]-mu)*rs*sc[c+e] + bi[c+e]);
  *(bf16x8*)(out + (size_t)row * DMODEL + c) = o8;
}

// ---------------- MFMA GEMM with global_load_lds + XOR-swizzled LDS ----------------
// LDS tile layout: rows of 64 bf16 (128B). Data for (row r, k-slot s) lives at
// physical slot p = s ^ (r&7). Staged via per-lane pre-swizzled GLOBAL address
// (rule #21: linear LDS dest + inverse-swizzled source + swizzled read).
// MODE 0: x = A@B + bias + pos_emb          (out f32 xbuf)       BM=128
// MODE 1: u=A@B0+b0, g=A@B1+b1 -> bf16(u*silu(g))  (bf16 obuf)   BM=64
// MODE 2: x = (x + A@B + bias) * decay      (f32 xbuf in-place)  BM=128
// MODE 3: out = mask ? A@B + bias : 0       (f32 fout)           BM=128
template<int MODE, int K>
__global__ __launch_bounds__(256) void gemm_k(
    const short* __restrict__ A, const short* __restrict__ B0, const short* __restrict__ B1,
    const float* __restrict__ bias0, const float* __restrict__ bias1,
    const float* __restrict__ pos, float* __restrict__ xbuf, short* __restrict__ obuf,
    float* __restrict__ fout, const void* __restrict__ mask, const int* __restrict__ flagp,
    int ldo)
{
  constexpr int BM = (MODE == 1) ? 64 : 128;
  constexpr int BN = 128;
  constexpr int NB = (MODE == 1) ? 2 : 1;
  constexpr int NJ = (MODE == 1) ? 2 : 4;   // n-frags per wave

  __shared__ short lds[(BM + BN * NB) * 64];
  short* lA  = lds;
  short* lB  = lds + BM * 64;
  short* lB2 = lds + (BM + BN) * 64;

  // bijective XCD swizzle (all grids have nwg % 8 == 0)
  const int nbx = gridDim.x;
  int bid = blockIdx.y * nbx + blockIdx.x;
  const int nwg = nbx * gridDim.y;
  bid = (bid & 7) * (nwg >> 3) + (bid >> 3);
  const int bx = bid % nbx, by = bid / nbx;
  const int n0 = bx * BN, m0 = by * BM;

  const int tid = threadIdx.x, lane = tid & 63, wid = tid >> 6;
  // staging lane decomposition: 1KB chunk = 8 rows x 128B; lane l -> row l/8, phys slot l%8
  const int lr  = lane >> 3;
  const int lks = (lane & 7) ^ (lr & 7);      // global k-slot this lane fetches
  // fragment read decomposition
  const int fr = lane & 15;                   // row within 16-row frag
  const int kg = lane >> 4;                   // k-group (8 elems each)

  const int wr = (MODE == 1) ? 0 : (wid >> 1);
  const int wc = (MODE == 1) ? wid : (wid & 1);
  const int rA0 = wr * 64 + fr;
  const int rB0 = wc * ((MODE == 1) ? 32 : 64) + fr;

  f32x4 acc[4][NJ];
  f32x4 acc2[(MODE == 1) ? 4 : 1][(MODE == 1) ? 2 : 1];
  const f32x4 zero = {0.f, 0.f, 0.f, 0.f};
  #pragma unroll
  for (int i = 0; i < 4; i++)
    #pragma unroll
    for (int j = 0; j < NJ; j++) acc[i][j] = zero;
  if constexpr (MODE == 1){
    #pragma unroll
    for (int i = 0; i < 4; i++)
      #pragma unroll
      for (int j = 0; j < 2; j++) acc2[i][j] = zero;
  }

  const short* Ab  = A  + (size_t)m0 * K + (size_t)lr * K + lks * 8;
  const short* B0b = B0 + (size_t)n0 * K + (size_t)lr * K + lks * 8;
  const short* B1b = (MODE == 1) ? (B1 + (size_t)n0 * K + (size_t)lr * K + lks * 8) : nullptr;

  for (int kt = 0; kt < K; kt += 64){
    __syncthreads();
    #pragma unroll
    for (int c = 0; c < BM / 32; c++)
      gl_lds16(Ab + kt + (size_t)(wid + c * 4) * 8 * K, lA + (wid + c * 4) * 512);
    #pragma unroll
    for (int c = 0; c < BN / 32; c++)
      gl_lds16(B0b + kt + (size_t)(wid + c * 4) * 8 * K, lB + (wid + c * 4) * 512);
    if constexpr (MODE == 1){
      #pragma unroll
      for (int c = 0; c < BN / 32; c++)
        gl_lds16(B1b + kt + (size_t)(wid + c * 4) * 8 * K, lB2 + (wid + c * 4) * 512);
    }
    __syncthreads();   // compiler emits vmcnt(0) drain before barrier -> tiles ready

    #pragma unroll
    for (int kb8 = 0; kb8 < 8; kb8 += 4){   // k-slot base: 0 (k 0..31), 4 (k 32..63)
      bf16x8 aF[4];
      #pragma unroll
      for (int i = 0; i < 4; i++){
        const int row = rA0 + i * 16;
        aF[i] = *(const bf16x8*)((const char*)lA + row * 128 + (((kg + kb8) ^ (row & 7)) * 16));
      }
      if constexpr (MODE == 1){
        bf16x8 bF[2], gF[2];
        #pragma unroll
        for (int j = 0; j < 2; j++){
          const int row = rB0 + j * 16;
          const int p = ((kg + kb8) ^ (row & 7)) * 16;
          bF[j] = *(const bf16x8*)((const char*)lB  + row * 128 + p);
          gF[j] = *(const bf16x8*)((const char*)lB2 + row * 128 + p);
        }
        #pragma unroll
        for (int i = 0; i < 4; i++)
          #pragma unroll
          for (int j = 0; j < 2; j++){
            acc[i][j]  = __builtin_amdgcn_mfma_f32_16x16x32_bf16(aF[i], bF[j], acc[i][j], 0, 0, 0);
            acc2[i][j] = __builtin_amdgcn_mfma_f32_16x16x32_bf16(aF[i], gF[j], acc2[i][j], 0, 0, 0);
          }
      } else {
        bf16x8 bF[4];
        #pragma unroll
        for (int j = 0; j < 4; j++){
          const int row = rB0 + j * 16;
          bF[j] = *(const bf16x8*)((const char*)lB + row * 128 + (((kg + kb8) ^ (row & 7)) * 16));
        }
        #pragma unroll
        for (int i = 0; i < 4; i++)
          #pragma unroll
          for (int j = 0; j < 4; j++)
            acc[i][j] = __builtin_amdgcn_mfma_f32_16x16x32_bf16(aF[i], bF[j], acc[i][j], 0, 0, 0);
      }
    }
  }

  // epilogue: C/D layout col = lane&15, row = (lane>>4)*4 + reg
  const int col0 = n0 + ((MODE == 1) ? wid * 32 : wc * 64) + fr;
  const int row0 = m0 + ((MODE == 1) ? 0 : wr * 64) + kg * 4;
  int flag = 0;
  if constexpr (MODE == 3) flag = *flagp;

  #pragma unroll
  for (int i = 0; i < 4; i++){
    #pragma unroll
    for (int r = 0; r < 4; r++){
      const int gm = row0 + i * 16 + r;
      #pragma unroll
      for (int j = 0; j < NJ; j++){
        const int gn = col0 + j * 16;
        float v = acc[i][j][r];
        if constexpr (MODE == 0){
          xbuf[(size_t)gm * ldo + gn] = v + bias0[gn] + pos[(size_t)(gm & (SEQ-1)) * DMODEL + gn];
        } else if constexpr (MODE == 1){
          float u = v + bias0[gn];
          float g = acc2[i][j][r] + bias1[gn];
          float sg = g / (1.0f + expf(-g));
          obuf[(size_t)gm * ldo + gn] = f2b(u * sg);
        } else if constexpr (MODE == 2){
          int s = gm & (SEQ-1);
          float d = (((s + 1) % 10) == 0) ? 0.1f : 1.0f;
          float y = v + bias0[gn];
          xbuf[(size_t)gm * ldo + gn] = (xbuf[(size_t)gm * ldo + gn] + y) * d;
        } else {
          bool mk = mask_at(mask, flag, gm);
          fout[(size_t)gm * ldo + gn] = mk ? (v + bias0[gn]) : 0.0f;
        }
      }
    }
  }
}

extern "C" void kernel_launch(void* const* d_in, const int* in_sizes, int n_in,
                              void* d_out, int out_size, void* d_ws, size_t ws_size,
                              hipStream_t stream){
  const float* frames    = (const float*)d_in[0];
  const void*  mask      = d_in[1];
  const float* W_in_proj = (const float*)d_in[2];
  const float* b_in_proj = (const float*)d_in[3];
  const float* pos_emb   = (const float*)d_in[4];
  const float* ln_scale  = (const float*)d_in[5];
  const float* ln_bias   = (const float*)d_in[6];
  const float* W_in      = (const float*)d_in[7];
  const float* b_in      = (const float*)d_in[8];
  const float* W_out     = (const float*)d_in[9];
  const float* b_out     = (const float*)d_in[10];
  const float* fn_scale  = (const float*)d_in[11];
  const float* fn_bias   = (const float*)d_in[12];
  const float* W_frame   = (const float*)d_in[13];
  const float* b_frame   = (const float*)d_in[14];
  const float* W_sym     = (const float*)d_in[15];
  const float* b_sym     = (const float*)d_in[16];

  char* w = (char*)d_ws;
  int*   flag = (int*)w;
  float* xbuf = (float*)(w + 256);                                    // 16384*512 f32
  short* nbuf = (short*)(w + 256 + 33554432);                         // 16384*512 bf16
  short* abuf = (short*)(w + 256 + 33554432 + 16777216);              // 16384*1024 bf16
  short* frb  = (short*)(w + 256 + 33554432 + 16777216 + 33554432);   // 16384*128 bf16
  short* Wt0  = frb + (size_t)16384 * 128;   // [512][128]
  short* Wt1  = Wt0 + (size_t)512 * 128;     // 4x [2048][512]
  short* Wt2  = Wt1 + (size_t)4 * 2048 * 512;// 4x [512][1024]
  short* Wt3  = Wt2 + (size_t)4 * 512 * 1024;// [128][512]
  short* Wt4  = Wt3 + (size_t)128 * 512;     // [256][512]

  detect_mask<<<1, 256, 0, stream>>>((const unsigned char*)mask, flag);
  cvt_bf16<<<2048, 256, 0, stream>>>(frames, frb);
  transpose_w<<<dim3(16,  4, 1), dim3(32, 8), 0, stream>>>(W_in_proj, Wt0, 128, 512);
  transpose_w<<<dim3(64, 16, 4), dim3(32, 8), 0, stream>>>(W_in,      Wt1, 512, 2048);
  transpose_w<<<dim3(16, 32, 4), dim3(32, 8), 0, stream>>>(W_out,     Wt2, 1024, 512);
  transpose_w<<<dim3(4,  16, 1), dim3(32, 8), 0, stream>>>(W_frame,   Wt3, 512, 128);
  transpose_w<<<dim3(8,  16, 1), dim3(32, 8), 0, stream>>>(W_sym,     Wt4, 512, 256);

  gemm_k<0, 128><<<dim3(4, 128), 256, 0, stream>>>(frb, Wt0, nullptr, b_in_proj, nullptr, pos_emb,
      xbuf, nullptr, nullptr, nullptr, nullptr, 512);

  for (int l = 0; l < 4; l++){
    ln_k<<<4096, 256, 0, stream>>>(xbuf, ln_scale + l*512, ln_bias + l*512, nbuf);
    gemm_k<1, 512><<<dim3(8, 256), 256, 0, stream>>>(nbuf,
        Wt1 + (size_t)l*2048*512, Wt1 + (size_t)l*2048*512 + (size_t)1024*512,
        b_in + l*2048, b_in + l*2048 + 1024, nullptr,
        nullptr, abuf, nullptr, nullptr, nullptr, 1024);
    gemm_k<2, 1024><<<dim3(4, 128), 256, 0, stream>>>(abuf, Wt2 + (size_t)l*512*1024, nullptr,
        b_out + l*512, nullptr, nullptr, xbuf, nullptr, nullptr, nullptr, nullptr, 512);
  }

  ln_k<<<4096, 256, 0, stream>>>(xbuf, fn_scale, fn_bias, nbuf);
  gemm_k<3, 512><<<dim3(1, 128), 256, 0, stream>>>(nbuf, Wt3, nullptr, b_frame, nullptr, nullptr,
      nullptr, nullptr, (float*)d_out, mask, flag, 128);
  gemm_k<3, 512><<<dim3(2, 128), 256, 0, stream>>>(nbuf, Wt4, nullptr, b_sym, nullptr, nullptr,
      nullptr, nullptr, (float*)d_out + (size_t)16384*128, mask, flag, 256);
}

// Round 3
// 573.966 us; speedup vs baseline: 1.3714x; 1.0141x over previous
//
#include <hip/hip_runtime.h>
#include <hip/hip_bf16.h>

using f32x4  = __attribute__((ext_vector_type(4))) float;
using bf16x8 = __attribute__((ext_vector_type(8))) short;
using bf16x4 = __attribute__((ext_vector_type(4))) short;

#define MTOT   16384
#define DMODEL 512
#define DINNER 1024
#define SEQ    2048

__device__ __forceinline__ short f2b(float f){
  unsigned u = __builtin_bit_cast(unsigned, f);
  u = (u + 0x7FFFu + ((u >> 16) & 1u)) >> 16;   // RNE
  return (short)u;
}

__device__ __forceinline__ void gl_lds16(const short* g, short* l){
  __builtin_amdgcn_global_load_lds(
      (const __attribute__((address_space(1))) void*)g,
      (__attribute__((address_space(3))) void*)l, 16, 0, 0);
}

// ---------------- mask layout detection (bool/u8 vs i32 vs f32 vs i64) ----------------
__global__ void detect_mask(const unsigned char* __restrict__ m, int* __restrict__ flag){
  __shared__ int sge2, soff, soff8;
  int tid = threadIdx.x;
  if (tid == 0){ sge2 = 0; soff = 0; soff8 = 0; }
  __syncthreads();
  int ge2 = 0, off = 0, off8 = 0;
  for (int i = tid; i < 16384; i += 256){
    unsigned char b = m[i];
    if (b >= 2) ge2++;
    if ((i & 3) && b) off++;
    if (((i & 7) == 4) && b) off8++;
  }
  atomicAdd(&sge2, ge2); atomicAdd(&soff, off); atomicAdd(&soff8, off8);
  __syncthreads();
  if (tid == 0){
    int f;
    if      (sge2 > 0) f = 2;   // float32 0.0/1.0
    else if (soff > 0) f = 1;   // bool / uint8
    else if (soff8 > 0) f = 0;  // int32
    else               f = 3;   // int64
    *flag = f;
  }
}

__device__ __forceinline__ bool mask_at(const void* mask, int flag, int m){
  if (flag == 1) return ((const unsigned char*)mask)[m] != 0;
  if (flag == 2) return ((const float*)mask)[m] != 0.0f;
  if (flag == 3) return ((const int*)mask)[2*m] != 0;
  return ((const int*)mask)[m] != 0;
}

// ---------------- f32 -> bf16 elementwise (frames) ----------------
__global__ void cvt_bf16(const float* __restrict__ in, short* __restrict__ out){
  int i = (blockIdx.x * 256 + threadIdx.x) * 4;
  float4 v = *(const float4*)(in + i);
  bf16x4 o; o[0] = f2b(v.x); o[1] = f2b(v.y); o[2] = f2b(v.z); o[3] = f2b(v.w);
  *(bf16x4*)(out + i) = o;
}

// ---------------- weight transpose+convert: f32 [R][C] -> bf16 [C][R] ----------------
// GLU=1: C = 2*DI; remap output row so u-col 16c+b -> 32c+b, g-col 16c+b -> 32c+16+b.
template<int GLU>
__global__ void transpose_w(const float* __restrict__ in, short* __restrict__ out, int R, int C){
  in  += (size_t)blockIdx.z * R * C;
  out += (size_t)blockIdx.z * R * C;
  __shared__ float t[32][33];
  int tx = threadIdx.x, ty = threadIdx.y;
  int r0 = blockIdx.y * 32, c0 = blockIdx.x * 32;
  #pragma unroll
  for (int i = 0; i < 4; i++)
    t[ty + i*8][tx] = in[(size_t)(r0 + ty + i*8) * C + c0 + tx];
  __syncthreads();
  #pragma unroll
  for (int i = 0; i < 4; i++){
    int oc = c0 + ty + i*8;            // original column index of W
    int nr;
    if constexpr (GLU){
      int half = C >> 1;
      nr = (oc < half) ? (((oc >> 4) << 5) + (oc & 15))
                       : ((((oc - half) >> 4) << 5) + 16 + (oc & 15));
    } else nr = oc;
    out[(size_t)nr * R + r0 + tx] = f2b(t[tx][ty + i*8]);
  }
}

// ---------------- LayerNorm: f32 x[row,512] -> bf16 out (wave per row) ----------------
__global__ __launch_bounds__(256) void ln_k(const float* __restrict__ x,
                                            const float* __restrict__ sc,
                                            const float* __restrict__ bi,
                                            short* __restrict__ out){
  int row  = blockIdx.x * 4 + (threadIdx.x >> 6);
  int lane = threadIdx.x & 63;
  const float* p = x + (size_t)row * DMODEL + lane * 8;
  float4 a = *(const float4*)p;
  float4 b = *(const float4*)(p + 4);
  float s = a.x+a.y+a.z+a.w + b.x+b.y+b.z+b.w;
  float q = a.x*a.x+a.y*a.y+a.z*a.z+a.w*a.w + b.x*b.x+b.y*b.y+b.z*b.z+b.w*b.w;
  #pragma unroll
  for (int o = 32; o >= 1; o >>= 1){ s += __shfl_xor(s, o); q += __shfl_xor(q, o); }
  float mu  = s * (1.0f/DMODEL);
  float var = q * (1.0f/DMODEL) - mu*mu;
  float rs  = rsqrtf(var + 1e-5f);
  int c = lane * 8;
  float vals[8] = {a.x,a.y,a.z,a.w,b.x,b.y,b.z,b.w};
  bf16x8 o8;
  #pragma unroll
  for (int e = 0; e < 8; e++) o8[e] = f2b((vals[e]-mu)*rs*sc[c+e] + bi[c+e]);
  *(bf16x8*)(out + (size_t)row * DMODEL + c) = o8;
}

// ---------------- MFMA GEMM 128x128, BK=64, global_load_lds + XOR-swizzled LDS ----------------
// LDS rows of 64 bf16 (128B); (row r, k-slot s) at phys slot s^(r&7); staged via
// pre-swizzled per-lane global source (linear LDS dest), read with swizzled ds_read.
// MODE 0: x = A@B + bias0 + pos_emb                       (f32 xbuf)
// MODE 1: GLU with interleaved B (u/g 16-col groups) -> bf16(u*silu(g)) obuf[.,1024]
// MODE 2: x = (x + A@B + bias0) * decay                   (f32 xbuf in-place)
// MODE 3: merged heads: n<128 frame (bias0, ld 128), else sym (bias1, ld 256); masked
template<int MODE, int K>
__global__ __launch_bounds__(256) void gemm_k(
    const short* __restrict__ A, const short* __restrict__ B,
    const float* __restrict__ bias0, const float* __restrict__ bias1,
    const float* __restrict__ pos, float* __restrict__ xbuf, short* __restrict__ obuf,
    float* __restrict__ fout, const void* __restrict__ mask, const int* __restrict__ flagp,
    int ldo)
{
  constexpr int BM = 128, BN = 128;
  __shared__ short lds[(BM + BN) * 64];
  short* lA = lds;
  short* lB = lds + BM * 64;

  // bijective XCD swizzle (all grids have nwg % 8 == 0)
  const int nbx = gridDim.x;
  int bid = blockIdx.y * nbx + blockIdx.x;
  const int nwg = nbx * gridDim.y;
  bid = (bid & 7) * (nwg >> 3) + (bid >> 3);
  const int bx = bid % nbx, by = bid / nbx;
  const int n0 = bx * BN, m0 = by * BM;

  const int tid = threadIdx.x, lane = tid & 63, wid = tid >> 6;
  // staging: 1KB chunk = 8 rows x 128B; lane l -> row l>>3, phys slot l&7
  const int lr  = lane >> 3;
  const int lks = (lane & 7) ^ (lr & 7);      // global k-slot this lane fetches
  // fragment read decomposition
  const int fr = lane & 15;
  const int kg = lane >> 4;

  const int wr = wid >> 1, wc = wid & 1;
  const int rA0 = wr * 64 + fr;
  const int rB0 = wc * 64 + fr;

  f32x4 acc[4][4];
  const f32x4 zero = {0.f, 0.f, 0.f, 0.f};
  #pragma unroll
  for (int i = 0; i < 4; i++)
    #pragma unroll
    for (int j = 0; j < 4; j++) acc[i][j] = zero;

  const short* Ab = A + (size_t)m0 * K + (size_t)lr * K + lks * 8;
  const short* Bb = B + (size_t)n0 * K + (size_t)lr * K + lks * 8;

  for (int kt = 0; kt < K; kt += 64){
    __syncthreads();
    #pragma unroll
    for (int c = 0; c < 4; c++)
      gl_lds16(Ab + kt + (size_t)(wid + c * 4) * 8 * K, lA + (wid + c * 4) * 512);
    #pragma unroll
    for (int c = 0; c < 4; c++)
      gl_lds16(Bb + kt + (size_t)(wid + c * 4) * 8 * K, lB + (wid + c * 4) * 512);
    __syncthreads();   // vmcnt(0) drain before barrier -> tiles ready

    #pragma unroll
    for (int kb8 = 0; kb8 < 8; kb8 += 4){   // k-slot base: 0 (k 0..31), 4 (k 32..63)
      bf16x8 aF[4], bF[4];
      #pragma unroll
      for (int i = 0; i < 4; i++){
        const int row = rA0 + i * 16;
        aF[i] = *(const bf16x8*)((const char*)lA + row * 128 + (((kg + kb8) ^ (row & 7)) * 16));
      }
      #pragma unroll
      for (int j = 0; j < 4; j++){
        const int row = rB0 + j * 16;
        bF[j] = *(const bf16x8*)((const char*)lB + row * 128 + (((kg + kb8) ^ (row & 7)) * 16));
      }
      #pragma unroll
      for (int i = 0; i < 4; i++)
        #pragma unroll
        for (int j = 0; j < 4; j++)
          acc[i][j] = __builtin_amdgcn_mfma_f32_16x16x32_bf16(aF[i], bF[j], acc[i][j], 0, 0, 0);
    }
  }

  // epilogue: C/D layout col = lane&15, row = (lane>>4)*4 + reg
  const int col0 = n0 + wc * 64 + fr;
  const int row0 = m0 + wr * 64 + kg * 4;
  int flag = 0;
  if constexpr (MODE == 3) flag = *flagp;

  #pragma unroll
  for (int i = 0; i < 4; i++){
    #pragma unroll
    for (int r = 0; r < 4; r++){
      const int gm = row0 + i * 16 + r;
      if constexpr (MODE == 1){
        // frags alternate u,g,u,g: acc[i][j] (u) pairs acc[i][j+1] (g), same lane
        #pragma unroll
        for (int jj = 0; jj < 2; jj++){
          const int j = 2 * jj;
          const int nb = n0 + wc * 64 + j * 16;            // physical frag base (mult of 32)
          const int lc = ((nb >> 5) << 4) + fr;            // logical u/g column 0..1023
          float u = acc[i][j][r]     + bias0[lc];
          float g = acc[i][j+1][r]   + bias0[1024 + lc];
          float sg = g / (1.0f + expf(-g));
          obuf[(size_t)gm * 1024 + lc] = f2b(u * sg);
        }
      } else {
        #pragma unroll
        for (int j = 0; j < 4; j++){
          const int gn = col0 + j * 16;
          float v = acc[i][j][r];
          if constexpr (MODE == 0){
            xbuf[(size_t)gm * ldo + gn] = v + bias0[gn] + pos[(size_t)(gm & (SEQ-1)) * DMODEL + gn];
          } else if constexpr (MODE == 2){
            int s = gm & (SEQ-1);
            float d = (((s + 1) % 10) == 0) ? 0.1f : 1.0f;
            float y = v + bias0[gn];
            xbuf[(size_t)gm * ldo + gn] = (xbuf[(size_t)gm * ldo + gn] + y) * d;
          } else {
            bool mk = mask_at(mask, flag, gm);
            if (gn < 128){
              fout[(size_t)gm * 128 + gn] = mk ? (v + bias0[gn]) : 0.0f;
            } else {
              int gs = gn - 128;
              fout[(size_t)16384 * 128 + (size_t)gm * 256 + gs] = mk ? (v + bias1[gs]) : 0.0f;
            }
          }
        }
      }
    }
  }
}

extern "C" void kernel_launch(void* const* d_in, const int* in_sizes, int n_in,
                              void* d_out, int out_size, void* d_ws, size_t ws_size,
                              hipStream_t stream){
  const float* frames    = (const float*)d_in[0];
  const void*  mask      = d_in[1];
  const float* W_in_proj = (const float*)d_in[2];
  const float* b_in_proj = (const float*)d_in[3];
  const float* pos_emb   = (const float*)d_in[4];
  const float* ln_scale  = (const float*)d_in[5];
  const float* ln_bias   = (const float*)d_in[6];
  const float* W_in      = (const float*)d_in[7];
  const float* b_in      = (const float*)d_in[8];
  const float* W_out     = (const float*)d_in[9];
  const float* b_out     = (const float*)d_in[10];
  const float* fn_scale  = (const float*)d_in[11];
  const float* fn_bias   = (const float*)d_in[12];
  const float* W_frame   = (const float*)d_in[13];
  const float* b_frame   = (const float*)d_in[14];
  const float* W_sym     = (const float*)d_in[15];
  const float* b_sym     = (const float*)d_in[16];

  char* w = (char*)d_ws;
  int*   flag = (int*)w;
  float* xbuf = (float*)(w + 256);                                    // 16384*512 f32
  short* nbuf = (short*)(w + 256 + 33554432);                         // 16384*512 bf16
  short* abuf = (short*)(w + 256 + 33554432 + 16777216);              // 16384*1024 bf16
  short* frb  = (short*)(w + 256 + 33554432 + 16777216 + 33554432);   // 16384*128 bf16
  short* Wt0  = frb + (size_t)16384 * 128;   // [512][128]
  short* Wt1  = Wt0 + (size_t)512 * 128;     // 4x [2048][512] (u/g interleaved 16-col groups)
  short* Wt2  = Wt1 + (size_t)4 * 2048 * 512;// 4x [512][1024]
  short* Wt3  = Wt2 + (size_t)4 * 512 * 1024;// [128][512]
  short* Wt4  = Wt3 + (size_t)128 * 512;     // [256][512]  (contiguous after Wt3)

  detect_mask<<<1, 256, 0, stream>>>((const unsigned char*)mask, flag);
  cvt_bf16<<<2048, 256, 0, stream>>>(frames, frb);
  transpose_w<0><<<dim3(16,  4, 1), dim3(32, 8), 0, stream>>>(W_in_proj, Wt0, 128, 512);
  transpose_w<1><<<dim3(64, 16, 4), dim3(32, 8), 0, stream>>>(W_in,      Wt1, 512, 2048);
  transpose_w<0><<<dim3(16, 32, 4), dim3(32, 8), 0, stream>>>(W_out,     Wt2, 1024, 512);
  transpose_w<0><<<dim3(4,  16, 1), dim3(32, 8), 0, stream>>>(W_frame,   Wt3, 512, 128);
  transpose_w<0><<<dim3(8,  16, 1), dim3(32, 8), 0, stream>>>(W_sym,     Wt4, 512, 256);

  gemm_k<0, 128><<<dim3(4, 128), 256, 0, stream>>>(frb, Wt0, b_in_proj, nullptr, pos_emb,
      xbuf, nullptr, nullptr, nullptr, nullptr, 512);

  for (int l = 0; l < 4; l++){
    ln_k<<<4096, 256, 0, stream>>>(xbuf, ln_scale + l*512, ln_bias + l*512, nbuf);
    gemm_k<1, 512><<<dim3(16, 128), 256, 0, stream>>>(nbuf,
        Wt1 + (size_t)l*2048*512, b_in + l*2048, nullptr, nullptr,
        nullptr, abuf, nullptr, nullptr, nullptr, 1024);
    gemm_k<2, 1024><<<dim3(4, 128), 256, 0, stream>>>(abuf, Wt2 + (size_t)l*512*1024,
        b_out + l*512, nullptr, nullptr, xbuf, nullptr, nullptr, nullptr, nullptr, 512);
  }

  ln_k<<<4096, 256, 0, stream>>>(xbuf, fn_scale, fn_bias, nbuf);
  gemm_k<3, 512><<<dim3(3, 128), 256, 0, stream>>>(nbuf, Wt3, b_frame, b_sym, nullptr,
      nullptr, nullptr, (float*)d_out, mask, flag, 0);
}

// Round 4
// 526.854 us; speedup vs baseline: 1.4940x; 1.0894x over previous
//
#include <hip/hip_runtime.h>
#include <hip/hip_bf16.h>

using f32x4  = __attribute__((ext_vector_type(4))) float;
using bf16x8 = __attribute__((ext_vector_type(8))) short;
using bf16x4 = __attribute__((ext_vector_type(4))) short;

#define MTOT   16384
#define DMODEL 512
#define DINNER 1024
#define SEQ    2048

__device__ __forceinline__ short f2b(float f){
  unsigned u = __builtin_bit_cast(unsigned, f);
  u = (u + 0x7FFFu + ((u >> 16) & 1u)) >> 16;   // RNE
  return (short)u;
}

__device__ __forceinline__ void gl_lds16(const short* g, short* l){
  __builtin_amdgcn_global_load_lds(
      (const __attribute__((address_space(1))) void*)g,
      (__attribute__((address_space(3))) void*)l, 16, 0, 0);
}

// ---------------- mask layout detection (bool/u8 vs i32 vs f32 vs i64) ----------------
__global__ void detect_mask(const unsigned char* __restrict__ m, int* __restrict__ flag){
  __shared__ int sge2, soff, soff8;
  int tid = threadIdx.x;
  if (tid == 0){ sge2 = 0; soff = 0; soff8 = 0; }
  __syncthreads();
  int ge2 = 0, off = 0, off8 = 0;
  for (int i = tid; i < 16384; i += 256){
    unsigned char b = m[i];
    if (b >= 2) ge2++;
    if ((i & 3) && b) off++;
    if (((i & 7) == 4) && b) off8++;
  }
  atomicAdd(&sge2, ge2); atomicAdd(&soff, off); atomicAdd(&soff8, off8);
  __syncthreads();
  if (tid == 0){
    int f;
    if      (sge2 > 0) f = 2;   // float32 0.0/1.0
    else if (soff > 0) f = 1;   // bool / uint8
    else if (soff8 > 0) f = 0;  // int32
    else               f = 3;   // int64
    *flag = f;
  }
}

__device__ __forceinline__ bool mask_at(const void* mask, int flag, int m){
  if (flag == 1) return ((const unsigned char*)mask)[m] != 0;
  if (flag == 2) return ((const float*)mask)[m] != 0.0f;
  if (flag == 3) return ((const int*)mask)[2*m] != 0;
  return ((const int*)mask)[m] != 0;
}

// ---------------- f32 -> bf16 elementwise (frames) ----------------
__global__ void cvt_bf16(const float* __restrict__ in, short* __restrict__ out){
  int i = (blockIdx.x * 256 + threadIdx.x) * 4;
  float4 v = *(const float4*)(in + i);
  bf16x4 o; o[0] = f2b(v.x); o[1] = f2b(v.y); o[2] = f2b(v.z); o[3] = f2b(v.w);
  *(bf16x4*)(out + i) = o;
}

// ---------------- weight transpose+convert: f32 [R][C] -> bf16 [C][R] ----------------
// GLU=1: C = 2*DI; remap output row so u-col 16c+b -> 32c+b, g-col 16c+b -> 32c+16+b.
template<int GLU>
__global__ void transpose_w(const float* __restrict__ in, short* __restrict__ out, int R, int C){
  in  += (size_t)blockIdx.z * R * C;
  out += (size_t)blockIdx.z * R * C;
  __shared__ float t[32][33];
  int tx = threadIdx.x, ty = threadIdx.y;
  int r0 = blockIdx.y * 32, c0 = blockIdx.x * 32;
  #pragma unroll
  for (int i = 0; i < 4; i++)
    t[ty + i*8][tx] = in[(size_t)(r0 + ty + i*8) * C + c0 + tx];
  __syncthreads();
  #pragma unroll
  for (int i = 0; i < 4; i++){
    int oc = c0 + ty + i*8;            // original column index of W
    int nr;
    if constexpr (GLU){
      int half = C >> 1;
      nr = (oc < half) ? (((oc >> 4) << 5) + (oc & 15))
                       : ((((oc - half) >> 4) << 5) + 16 + (oc & 15));
    } else nr = oc;
    out[(size_t)nr * R + r0 + tx] = f2b(t[tx][ty + i*8]);
  }
}

// ---------------- LayerNorm: f32 x[row,512] -> bf16 out (wave per row) ----------------
__global__ __launch_bounds__(256) void ln_k(const float* __restrict__ x,
                                            const float* __restrict__ sc,
                                            const float* __restrict__ bi,
                                            short* __restrict__ out){
  int row  = blockIdx.x * 4 + (threadIdx.x >> 6);
  int lane = threadIdx.x & 63;
  const float* p = x + (size_t)row * DMODEL + lane * 8;
  float4 a = *(const float4*)p;
  float4 b = *(const float4*)(p + 4);
  float s = a.x+a.y+a.z+a.w + b.x+b.y+b.z+b.w;
  float q = a.x*a.x+a.y*a.y+a.z*a.z+a.w*a.w + b.x*b.x+b.y*b.y+b.z*b.z+b.w*b.w;
  #pragma unroll
  for (int o = 32; o >= 1; o >>= 1){ s += __shfl_xor(s, o); q += __shfl_xor(q, o); }
  float mu  = s * (1.0f/DMODEL);
  float var = q * (1.0f/DMODEL) - mu*mu;
  float rs  = rsqrtf(var + 1e-5f);
  int c = lane * 8;
  float vals[8] = {a.x,a.y,a.z,a.w,b.x,b.y,b.z,b.w};
  bf16x8 o8;
  #pragma unroll
  for (int e = 0; e < 8; e++) o8[e] = f2b((vals[e]-mu)*rs*sc[c+e] + bi[c+e]);
  *(bf16x8*)(out + (size_t)row * DMODEL + c) = o8;
}

// ================= GLU 256x256 8-phase MFMA GEMM (T2+T3+T4+T5) =================
// 8 waves (2M x 4N), BK=64, LDS = 8 slots x 16KB (half-tile = 128 rows x 64 cols).
// Half-tile sequence per K-tile: [Ah0, Ah1, Bh0, Bh1]; slot = half_index & 7.
// Staging: 1 half-tile/phase at distance 6 phases ahead; counted vmcnt(4) once
// per K-tile (p3), vmcnt(0) only at drain. Raw s_barrier (no vmcnt0 drain),
// sched_barrier fences, setprio around MFMA. XOR swizzle: (row, kslot s) at
// phys slot s^(row&7) in the 128B row (proven 0-conflict in prior rounds).
template<int K>
__global__ __launch_bounds__(512, 2) void glu8p(
    const short* __restrict__ A, const short* __restrict__ B,
    const float* __restrict__ bias, short* __restrict__ obuf)
{
  constexpr int NT = K / 64;
  constexpr int HT = NT * 4;
  __shared__ short lds[8 * 8192];   // 128 KiB

  const int nbx = gridDim.x;
  int bid = blockIdx.y * nbx + blockIdx.x;
  const int nwg = nbx * gridDim.y;
  bid = (bid & 7) * (nwg >> 3) + (bid >> 3);   // bijective XCD swizzle (nwg%8==0)
  const int n0 = (bid % nbx) * 256, m0 = (bid / nbx) * 256;

  const int tid = threadIdx.x, lane = tid & 63, wid = tid >> 6;
  const int wr = wid >> 2, wc = wid & 3;       // wave grid 2M x 4N
  const int fr = lane & 15, kg = lane >> 4;

  f32x4 acc[8][2][2];
  const f32x4 zero = {0.f, 0.f, 0.f, 0.f};
  #pragma unroll
  for (int i = 0; i < 8; i++)
    #pragma unroll
    for (int nh = 0; nh < 2; nh++)
      #pragma unroll
      for (int j = 0; j < 2; j++) acc[i][nh][j] = zero;

  // per-thread staging offsets (pre-swizzled global source, linear LDS dest)
  const int rl0 = wid * 8 + (lane >> 3);
  const int swz = ((lane & 7) ^ ((lane >> 3) & 7)) * 8;
  const short* Ab = A + ((size_t)m0 + rl0) * K + swz;
  const short* Bb = B + ((size_t)n0 + rl0) * K + swz;

  auto stage = [&](int h){
    if (h < HT){
      const int q = h & 3, kt = h >> 2, slot = h & 7;
      const short* src = (q < 2) ? (Ab + (size_t)(q * 128) * K + kt * 64)
                                 : (Bb + (size_t)((q - 2) * 128) * K + kt * 64);
      short* dst = lds + slot * 8192 + wid * 512;
      gl_lds16(src, dst);
      gl_lds16(src + (size_t)64 * K, dst + 4096);
    }
  };

  // prologue: 6 half-tiles ahead, first K-tile fully landed after vmcnt(4)+barrier
  #pragma unroll
  for (int h = 0; h < 6; h++) stage(h);
  asm volatile("s_waitcnt vmcnt(4)" ::: "memory");
  __builtin_amdgcn_sched_barrier(0);
  __builtin_amdgcn_s_barrier();
  __builtin_amdgcn_sched_barrier(0);

  for (int kt = 0; kt < NT; ++kt){
    bf16x8 aF[8];
    #pragma unroll
    for (int p = 0; p < 4; ++p){
      const int kb = p >> 1, nh = p & 1;
      const int ks = kg + kb * 4;
      if (nh == 0){
        const int slot = (4 * kt + wr) & 7;
        #pragma unroll
        for (int i = 0; i < 8; i++)
          aF[i] = *(const bf16x8*)((const char*)lds + slot * 16384
                     + (i * 16 + fr) * 128 + ((ks ^ (fr & 7)) * 16));
      }
      bf16x8 bF[2];
      {
        const int slot = (4 * kt + 2 + nh) & 7;
        #pragma unroll
        for (int j = 0; j < 2; j++)
          bF[j] = *(const bf16x8*)((const char*)lds + slot * 16384
                     + (wc * 32 + j * 16 + fr) * 128 + ((ks ^ (fr & 7)) * 16));
      }
      stage(4 * kt + p + 6);
      if (p == 3){
        if (kt < NT - 2)       asm volatile("s_waitcnt vmcnt(4)" ::: "memory");
        else if (kt == NT - 2) asm volatile("s_waitcnt vmcnt(0)" ::: "memory");
      }
      __builtin_amdgcn_sched_barrier(0);
      __builtin_amdgcn_s_barrier();
      __builtin_amdgcn_sched_barrier(0);
      __builtin_amdgcn_s_setprio(1);
      #pragma unroll
      for (int i = 0; i < 8; i++)
        #pragma unroll
        for (int j = 0; j < 2; j++)
          acc[i][nh][j] = __builtin_amdgcn_mfma_f32_16x16x32_bf16(aF[i], bF[j], acc[i][nh][j], 0, 0, 0);
      __builtin_amdgcn_s_setprio(0);
      __builtin_amdgcn_sched_barrier(0);
      __builtin_amdgcn_s_barrier();
      __builtin_amdgcn_sched_barrier(0);
    }
  }

  // epilogue: frag j=0 is u (cols 32c+0..15), j=1 is g (cols 32c+16..31)
  #pragma unroll
  for (int i = 0; i < 8; i++){
    #pragma unroll
    for (int nh = 0; nh < 2; nh++){
      const int pc = n0 + nh * 128 + wc * 32;       // physical col base (mult of 32)
      const int lc = ((pc >> 5) << 4) + fr;         // logical u/g column 0..1023
      #pragma unroll
      for (int r = 0; r < 4; r++){
        const int gm = m0 + wr * 128 + i * 16 + kg * 4 + r;
        float u = acc[i][nh][0][r] + bias[lc];
        float g = acc[i][nh][1][r] + bias[1024 + lc];
        float sg = g / (1.0f + expf(-g));
        obuf[(size_t)gm * 1024 + lc] = f2b(u * sg);
      }
    }
  }
}

// ---------------- MFMA GEMM 128x128, BK=64, global_load_lds + XOR-swizzled LDS ----------------
// MODE 0: x = A@B + bias0 + pos_emb                       (f32 xbuf)
// MODE 2: x = (x + A@B + bias0) * decay                   (f32 xbuf in-place)
// MODE 3: merged heads: n<128 frame (bias0, ld 128), else sym (bias1, ld 256); masked
template<int MODE, int K>
__global__ __launch_bounds__(256) void gemm_k(
    const short* __restrict__ A, const short* __restrict__ B,
    const float* __restrict__ bias0, const float* __restrict__ bias1,
    const float* __restrict__ pos, float* __restrict__ xbuf, short* __restrict__ obuf,
    float* __restrict__ fout, const void* __restrict__ mask, const int* __restrict__ flagp,
    int ldo)
{
  constexpr int BM = 128, BN = 128;
  __shared__ short lds[(BM + BN) * 64];
  short* lA = lds;
  short* lB = lds + BM * 64;

  const int nbx = gridDim.x;
  int bid = blockIdx.y * nbx + blockIdx.x;
  const int nwg = nbx * gridDim.y;
  bid = (bid & 7) * (nwg >> 3) + (bid >> 3);
  const int bx = bid % nbx, by = bid / nbx;
  const int n0 = bx * BN, m0 = by * BM;

  const int tid = threadIdx.x, lane = tid & 63, wid = tid >> 6;
  const int lr  = lane >> 3;
  const int lks = (lane & 7) ^ (lr & 7);
  const int fr = lane & 15;
  const int kg = lane >> 4;

  const int wr = wid >> 1, wc = wid & 1;
  const int rA0 = wr * 64 + fr;
  const int rB0 = wc * 64 + fr;

  f32x4 acc[4][4];
  const f32x4 zero = {0.f, 0.f, 0.f, 0.f};
  #pragma unroll
  for (int i = 0; i < 4; i++)
    #pragma unroll
    for (int j = 0; j < 4; j++) acc[i][j] = zero;

  const short* Ab = A + (size_t)m0 * K + (size_t)lr * K + lks * 8;
  const short* Bb = B + (size_t)n0 * K + (size_t)lr * K + lks * 8;

  for (int kt = 0; kt < K; kt += 64){
    __syncthreads();
    #pragma unroll
    for (int c = 0; c < 4; c++)
      gl_lds16(Ab + kt + (size_t)(wid + c * 4) * 8 * K, lA + (wid + c * 4) * 512);
    #pragma unroll
    for (int c = 0; c < 4; c++)
      gl_lds16(Bb + kt + (size_t)(wid + c * 4) * 8 * K, lB + (wid + c * 4) * 512);
    __syncthreads();

    #pragma unroll
    for (int kb8 = 0; kb8 < 8; kb8 += 4){
      bf16x8 aF[4], bF[4];
      #pragma unroll
      for (int i = 0; i < 4; i++){
        const int row = rA0 + i * 16;
        aF[i] = *(const bf16x8*)((const char*)lA + row * 128 + (((kg + kb8) ^ (row & 7)) * 16));
      }
      #pragma unroll
      for (int j = 0; j < 4; j++){
        const int row = rB0 + j * 16;
        bF[j] = *(const bf16x8*)((const char*)lB + row * 128 + (((kg + kb8) ^ (row & 7)) * 16));
      }
      #pragma unroll
      for (int i = 0; i < 4; i++)
        #pragma unroll
        for (int j = 0; j < 4; j++)
          acc[i][j] = __builtin_amdgcn_mfma_f32_16x16x32_bf16(aF[i], bF[j], acc[i][j], 0, 0, 0);
    }
  }

  const int col0 = n0 + wc * 64 + fr;
  const int row0 = m0 + wr * 64 + kg * 4;
  int flag = 0;
  if constexpr (MODE == 3) flag = *flagp;

  #pragma unroll
  for (int i = 0; i < 4; i++){
    #pragma unroll
    for (int r = 0; r < 4; r++){
      const int gm = row0 + i * 16 + r;
      #pragma unroll
      for (int j = 0; j < 4; j++){
        const int gn = col0 + j * 16;
        float v = acc[i][j][r];
        if constexpr (MODE == 0){
          xbuf[(size_t)gm * ldo + gn] = v + bias0[gn] + pos[(size_t)(gm & (SEQ-1)) * DMODEL + gn];
        } else if constexpr (MODE == 2){
          int s = gm & (SEQ-1);
          float d = (((s + 1) % 10) == 0) ? 0.1f : 1.0f;
          float y = v + bias0[gn];
          xbuf[(size_t)gm * ldo + gn] = (xbuf[(size_t)gm * ldo + gn] + y) * d;
        } else {
          bool mk = mask_at(mask, flag, gm);
          if (gn < 128){
            fout[(size_t)gm * 128 + gn] = mk ? (v + bias0[gn]) : 0.0f;
          } else {
            int gs = gn - 128;
            fout[(size_t)16384 * 128 + (size_t)gm * 256 + gs] = mk ? (v + bias1[gs]) : 0.0f;
          }
        }
      }
    }
  }
}

extern "C" void kernel_launch(void* const* d_in, const int* in_sizes, int n_in,
                              void* d_out, int out_size, void* d_ws, size_t ws_size,
                              hipStream_t stream){
  const float* frames    = (const float*)d_in[0];
  const void*  mask      = d_in[1];
  const float* W_in_proj = (const float*)d_in[2];
  const float* b_in_proj = (const float*)d_in[3];
  const float* pos_emb   = (const float*)d_in[4];
  const float* ln_scale  = (const float*)d_in[5];
  const float* ln_bias   = (const float*)d_in[6];
  const float* W_in      = (const float*)d_in[7];
  const float* b_in      = (const float*)d_in[8];
  const float* W_out     = (const float*)d_in[9];
  const float* b_out     = (const float*)d_in[10];
  const float* fn_scale  = (const float*)d_in[11];
  const float* fn_bias   = (const float*)d_in[12];
  const float* W_frame   = (const float*)d_in[13];
  const float* b_frame   = (const float*)d_in[14];
  const float* W_sym     = (const float*)d_in[15];
  const float* b_sym     = (const float*)d_in[16];

  char* w = (char*)d_ws;
  int*   flag = (int*)w;
  float* xbuf = (float*)(w + 256);                                    // 16384*512 f32
  short* nbuf = (short*)(w + 256 + 33554432);                         // 16384*512 bf16
  short* abuf = (short*)(w + 256 + 33554432 + 16777216);              // 16384*1024 bf16
  short* frb  = (short*)(w + 256 + 33554432 + 16777216 + 33554432);   // 16384*128 bf16
  short* Wt0  = frb + (size_t)16384 * 128;   // [512][128]
  short* Wt1  = Wt0 + (size_t)512 * 128;     // 4x [2048][512] (u/g interleaved 16-col groups)
  short* Wt2  = Wt1 + (size_t)4 * 2048 * 512;// 4x [512][1024]
  short* Wt3  = Wt2 + (size_t)4 * 512 * 1024;// [128][512]
  short* Wt4  = Wt3 + (size_t)128 * 512;     // [256][512]  (contiguous after Wt3)

  detect_mask<<<1, 256, 0, stream>>>((const unsigned char*)mask, flag);
  cvt_bf16<<<2048, 256, 0, stream>>>(frames, frb);
  transpose_w<0><<<dim3(16,  4, 1), dim3(32, 8), 0, stream>>>(W_in_proj, Wt0, 128, 512);
  transpose_w<1><<<dim3(64, 16, 4), dim3(32, 8), 0, stream>>>(W_in,      Wt1, 512, 2048);
  transpose_w<0><<<dim3(16, 32, 4), dim3(32, 8), 0, stream>>>(W_out,     Wt2, 1024, 512);
  transpose_w<0><<<dim3(4,  16, 1), dim3(32, 8), 0, stream>>>(W_frame,   Wt3, 512, 128);
  transpose_w<0><<<dim3(8,  16, 1), dim3(32, 8), 0, stream>>>(W_sym,     Wt4, 512, 256);

  gemm_k<0, 128><<<dim3(4, 128), 256, 0, stream>>>(frb, Wt0, b_in_proj, nullptr, pos_emb,
      xbuf, nullptr, nullptr, nullptr, nullptr, 512);

  for (int l = 0; l < 4; l++){
    ln_k<<<4096, 256, 0, stream>>>(xbuf, ln_scale + l*512, ln_bias + l*512, nbuf);
    glu8p<512><<<dim3(8, 64), 512, 0, stream>>>(nbuf,
        Wt1 + (size_t)l*2048*512, b_in + l*2048, abuf);
    gemm_k<2, 1024><<<dim3(4, 128), 256, 0, stream>>>(abuf, Wt2 + (size_t)l*512*1024,
        b_out + l*512, nullptr, nullptr, xbuf, nullptr, nullptr, nullptr, nullptr, 512);
  }

  ln_k<<<4096, 256, 0, stream>>>(xbuf, fn_scale, fn_bias, nbuf);
  gemm_k<3, 512><<<dim3(3, 128), 256, 0, stream>>>(nbuf, Wt3, b_frame, b_sym, nullptr,
      nullptr, nullptr, (float*)d_out, mask, flag, 0);
}

// Round 5
// 519.304 us; speedup vs baseline: 1.5157x; 1.0145x over previous
//
#include <hip/hip_runtime.h>
#include <hip/hip_bf16.h>

using f32x4  = __attribute__((ext_vector_type(4))) float;
using bf16x8 = __attribute__((ext_vector_type(8))) short;
using bf16x4 = __attribute__((ext_vector_type(4))) short;

#define MTOT   16384
#define DMODEL 512
#define DINNER 1024
#define SEQ    2048

__device__ __forceinline__ short f2b(float f){
  unsigned u = __builtin_bit_cast(unsigned, f);
  u = (u + 0x7FFFu + ((u >> 16) & 1u)) >> 16;   // RNE
  return (short)u;
}

__device__ __forceinline__ void gl_lds16(const short* g, short* l){
  __builtin_amdgcn_global_load_lds(
      (const __attribute__((address_space(1))) void*)g,
      (__attribute__((address_space(3))) void*)l, 16, 0, 0);
}

// ---------------- mask layout detection (bool/u8 vs i32 vs f32 vs i64) ----------------
__global__ void detect_mask(const unsigned char* __restrict__ m, int* __restrict__ flag){
  __shared__ int sge2, soff, soff8;
  int tid = threadIdx.x;
  if (tid == 0){ sge2 = 0; soff = 0; soff8 = 0; }
  __syncthreads();
  int ge2 = 0, off = 0, off8 = 0;
  for (int i = tid; i < 16384; i += 256){
    unsigned char b = m[i];
    if (b >= 2) ge2++;
    if ((i & 3) && b) off++;
    if (((i & 7) == 4) && b) off8++;
  }
  atomicAdd(&sge2, ge2); atomicAdd(&soff, off); atomicAdd(&soff8, off8);
  __syncthreads();
  if (tid == 0){
    int f;
    if      (sge2 > 0) f = 2;   // float32 0.0/1.0
    else if (soff > 0) f = 1;   // bool / uint8
    else if (soff8 > 0) f = 0;  // int32
    else               f = 3;   // int64
    *flag = f;
  }
}

__device__ __forceinline__ bool mask_at(const void* mask, int flag, int m){
  if (flag == 1) return ((const unsigned char*)mask)[m] != 0;
  if (flag == 2) return ((const float*)mask)[m] != 0.0f;
  if (flag == 3) return ((const int*)mask)[2*m] != 0;
  return ((const int*)mask)[m] != 0;
}

// ---------------- f32 -> bf16 elementwise (frames) ----------------
__global__ void cvt_bf16(const float* __restrict__ in, short* __restrict__ out){
  int i = (blockIdx.x * 256 + threadIdx.x) * 4;
  float4 v = *(const float4*)(in + i);
  bf16x4 o; o[0] = f2b(v.x); o[1] = f2b(v.y); o[2] = f2b(v.z); o[3] = f2b(v.w);
  *(bf16x4*)(out + i) = o;
}

// ---------------- weight transpose+convert: f32 [R][C] -> bf16 [C][R] ----------------
// GLU=1: C = 2*DI; remap output row so u-col 16c+b -> 32c+b, g-col 16c+b -> 32c+16+b.
template<int GLU>
__global__ void transpose_w(const float* __restrict__ in, short* __restrict__ out, int R, int C){
  in  += (size_t)blockIdx.z * R * C;
  out += (size_t)blockIdx.z * R * C;
  __shared__ float t[32][33];
  int tx = threadIdx.x, ty = threadIdx.y;
  int r0 = blockIdx.y * 32, c0 = blockIdx.x * 32;
  #pragma unroll
  for (int i = 0; i < 4; i++)
    t[ty + i*8][tx] = in[(size_t)(r0 + ty + i*8) * C + c0 + tx];
  __syncthreads();
  #pragma unroll
  for (int i = 0; i < 4; i++){
    int oc = c0 + ty + i*8;            // original column index of W
    int nr;
    if constexpr (GLU){
      int half = C >> 1;
      nr = (oc < half) ? (((oc >> 4) << 5) + (oc & 15))
                       : ((((oc - half) >> 4) << 5) + 16 + (oc & 15));
    } else nr = oc;
    out[(size_t)nr * R + r0 + tx] = f2b(t[tx][ty + i*8]);
  }
}

// ---------------- LayerNorm: f32 x[row,512] -> bf16 out (wave per row) ----------------
__global__ __launch_bounds__(256) void ln_k(const float* __restrict__ x,
                                            const float* __restrict__ sc,
                                            const float* __restrict__ bi,
                                            short* __restrict__ out){
  int row  = blockIdx.x * 4 + (threadIdx.x >> 6);
  int lane = threadIdx.x & 63;
  const float* p = x + (size_t)row * DMODEL + lane * 8;
  float4 a = *(const float4*)p;
  float4 b = *(const float4*)(p + 4);
  float s = a.x+a.y+a.z+a.w + b.x+b.y+b.z+b.w;
  float q = a.x*a.x+a.y*a.y+a.z*a.z+a.w*a.w + b.x*b.x+b.y*b.y+b.z*b.z+b.w*b.w;
  #pragma unroll
  for (int o = 32; o >= 1; o >>= 1){ s += __shfl_xor(s, o); q += __shfl_xor(q, o); }
  float mu  = s * (1.0f/DMODEL);
  float var = q * (1.0f/DMODEL) - mu*mu;
  float rs  = rsqrtf(var + 1e-5f);
  int c = lane * 8;
  float vals[8] = {a.x,a.y,a.z,a.w,b.x,b.y,b.z,b.w};
  bf16x8 o8;
  #pragma unroll
  for (int e = 0; e < 8; e++) o8[e] = f2b((vals[e]-mu)*rs*sc[c+e] + bi[c+e]);
  *(bf16x8*)(out + (size_t)row * DMODEL + c) = o8;
}

// ================= GLU 256x256 8-phase MFMA GEMM (T2+T3+T4+T5) =================
// 8 waves (2M x 4N), BK=64, LDS = 8 slots x 16KB (half-tile = 128 rows x 64 cols).
// Half-tile sequence per K-tile: [Ah0, Ah1, Bh0, Bh1]; slot = half_index & 7.
// Staging: 1 half-tile/phase at distance 6; counted vmcnt(4) once per K-tile.
// NO sched_barrier fences (m141: order-pinning defeats compiler scheduling).
template<int K>
__global__ __launch_bounds__(512, 2) void glu8p(
    const short* __restrict__ A, const short* __restrict__ B,
    const float* __restrict__ bias, short* __restrict__ obuf)
{
  constexpr int NT = K / 64;
  constexpr int HT = NT * 4;
  __shared__ short lds[8 * 8192];   // 128 KiB

  const int nbx = gridDim.x;
  int bid = blockIdx.y * nbx + blockIdx.x;
  const int nwg = nbx * gridDim.y;
  bid = (bid & 7) * (nwg >> 3) + (bid >> 3);   // bijective XCD swizzle (nwg%8==0)
  const int n0 = (bid % nbx) * 256, m0 = (bid / nbx) * 256;

  const int tid = threadIdx.x, lane = tid & 63, wid = tid >> 6;
  const int wr = wid >> 2, wc = wid & 3;       // wave grid 2M x 4N
  const int fr = lane & 15, kg = lane >> 4;

  f32x4 acc[8][2][2];
  const f32x4 zero = {0.f, 0.f, 0.f, 0.f};
  #pragma unroll
  for (int i = 0; i < 8; i++)
    #pragma unroll
    for (int nh = 0; nh < 2; nh++)
      #pragma unroll
      for (int j = 0; j < 2; j++) acc[i][nh][j] = zero;

  // per-thread staging offsets (pre-swizzled global source, linear LDS dest)
  const int rl0 = wid * 8 + (lane >> 3);
  const int swz = ((lane & 7) ^ ((lane >> 3) & 7)) * 8;
  const short* Ab = A + ((size_t)m0 + rl0) * K + swz;
  const short* Bb = B + ((size_t)n0 + rl0) * K + swz;

  auto stage = [&](int h){
    if (h < HT){
      const int q = h & 3, kt = h >> 2, slot = h & 7;
      const short* src = (q < 2) ? (Ab + (size_t)(q * 128) * K + kt * 64)
                                 : (Bb + (size_t)((q - 2) * 128) * K + kt * 64);
      short* dst = lds + slot * 8192 + wid * 512;
      gl_lds16(src, dst);
      gl_lds16(src + (size_t)64 * K, dst + 4096);
    }
  };

  #pragma unroll
  for (int h = 0; h < 6; h++) stage(h);
  asm volatile("s_waitcnt vmcnt(4)" ::: "memory");
  __builtin_amdgcn_s_barrier();

  for (int kt = 0; kt < NT; ++kt){
    bf16x8 aF[8];
    #pragma unroll
    for (int p = 0; p < 4; ++p){
      const int kb = p >> 1, nh = p & 1;
      const int ks = kg + kb * 4;
      if (nh == 0){
        const int slot = (4 * kt + wr) & 7;
        #pragma unroll
        for (int i = 0; i < 8; i++)
          aF[i] = *(const bf16x8*)((const char*)lds + slot * 16384
                     + (i * 16 + fr) * 128 + ((ks ^ (fr & 7)) * 16));
      }
      bf16x8 bF[2];
      {
        const int slot = (4 * kt + 2 + nh) & 7;
        #pragma unroll
        for (int j = 0; j < 2; j++)
          bF[j] = *(const bf16x8*)((const char*)lds + slot * 16384
                     + (wc * 32 + j * 16 + fr) * 128 + ((ks ^ (fr & 7)) * 16));
      }
      stage(4 * kt + p + 6);
      if (p == 3){
        if (kt < NT - 2)       asm volatile("s_waitcnt vmcnt(4)" ::: "memory");
        else if (kt == NT - 2) asm volatile("s_waitcnt vmcnt(0)" ::: "memory");
      }
      __builtin_amdgcn_s_barrier();
      __builtin_amdgcn_s_setprio(1);
      #pragma unroll
      for (int i = 0; i < 8; i++)
        #pragma unroll
        for (int j = 0; j < 2; j++)
          acc[i][nh][j] = __builtin_amdgcn_mfma_f32_16x16x32_bf16(aF[i], bF[j], acc[i][nh][j], 0, 0, 0);
      __builtin_amdgcn_s_setprio(0);
      __builtin_amdgcn_s_barrier();
    }
  }

  // epilogue: frag j=0 is u (cols 32c+0..15), j=1 is g (cols 32c+16..31)
  #pragma unroll
  for (int i = 0; i < 8; i++){
    #pragma unroll
    for (int nh = 0; nh < 2; nh++){
      const int pc = n0 + nh * 128 + wc * 32;       // physical col base (mult of 32)
      const int lc = ((pc >> 5) << 4) + fr;         // logical u/g column 0..1023
      #pragma unroll
      for (int r = 0; r < 4; r++){
        const int gm = m0 + wr * 128 + i * 16 + kg * 4 + r;
        float u = acc[i][nh][0][r] + bias[lc];
        float g = acc[i][nh][1][r] + bias[1024 + lc];
        float sg = g / (1.0f + expf(-g));
        obuf[(size_t)gm * 1024 + lc] = f2b(u * sg);
      }
    }
  }
}

// ================= residual GEMM 128x256 8-phase (x = (x + A@B + b)*decay) =================
// 8 waves (2M x 4N, wave 64x64), BK=64, U=3 units/K-tile (A, Bh0, Bh1), 16KB units,
// ring of 9 slots (144 KiB) -> slot reuse distance = 3 K-tiles. Stage all 3 units of
// tile kt+2 at kb0; vmcnt(6) once per K-tile at kb1; vmcnt(0) only at drain.
template<int K>
__global__ __launch_bounds__(512, 2) void res8p(
    const short* __restrict__ A, const short* __restrict__ B,
    const float* __restrict__ bias, float* __restrict__ xbuf)
{
  constexpr int NT = K / 64;          // 16
  __shared__ short lds[9 * 8192];     // 144 KiB

  const int nbx = gridDim.x;          // 2
  int bid = blockIdx.y * nbx + blockIdx.x;
  const int nwg = nbx * gridDim.y;
  bid = (bid & 7) * (nwg >> 3) + (bid >> 3);
  const int n0 = (bid % nbx) * 256, m0 = (bid / nbx) * 128;

  const int lane = threadIdx.x & 63, wid = threadIdx.x >> 6;
  const int wr = wid >> 2, wc = wid & 3;
  const int fr = lane & 15, kg = lane >> 4;

  f32x4 acc[4][4];
  const f32x4 zero = {0.f, 0.f, 0.f, 0.f};
  #pragma unroll
  for (int i = 0; i < 4; i++)
    #pragma unroll
    for (int j = 0; j < 4; j++) acc[i][j] = zero;

  const int rl0 = wid * 8 + (lane >> 3);
  const int swz = ((lane & 7) ^ ((lane >> 3) & 7)) * 8;
  const short* Ab = A + ((size_t)m0 + rl0) * K + swz;
  const short* Bb = B + ((size_t)n0 + rl0) * K + swz;

  auto stage_tile = [&](int m){
    if (m < NT){
      const int s0 = (3 * m) % 9;
      short* d0 = lds + s0 * 8192 + wid * 512;
      const short* gA = Ab + m * 64;
      gl_lds16(gA, d0);
      gl_lds16(gA + (size_t)64 * K, d0 + 4096);
      const int s1 = (3 * m + 1) % 9;
      short* d1 = lds + s1 * 8192 + wid * 512;
      const short* gB0 = Bb + m * 64;
      gl_lds16(gB0, d1);
      gl_lds16(gB0 + (size_t)64 * K, d1 + 4096);
      const int s2 = (3 * m + 2) % 9;
      short* d2 = lds + s2 * 8192 + wid * 512;
      const short* gB1 = Bb + (size_t)128 * K + m * 64;
      gl_lds16(gB1, d2);
      gl_lds16(gB1 + (size_t)64 * K, d2 + 4096);
    }
  };

  stage_tile(0); stage_tile(1);
  asm volatile("s_waitcnt vmcnt(6)" ::: "memory");
  __builtin_amdgcn_s_barrier();

  for (int kt = 0; kt < NT; ++kt){
    const int sA = (3 * kt) % 9;
    const int sB = (3 * kt + 1 + (wc >> 1)) % 9;
    #pragma unroll
    for (int kb = 0; kb < 2; kb++){
      const int ks = kg + kb * 4;
      bf16x8 aF[4], bF[4];
      #pragma unroll
      for (int i = 0; i < 4; i++){
        const int row = wr * 64 + i * 16 + fr;
        aF[i] = *(const bf16x8*)((const char*)lds + sA * 16384
                   + row * 128 + ((ks ^ (row & 7)) * 16));
      }
      #pragma unroll
      for (int j = 0; j < 4; j++){
        const int row = (wc & 1) * 64 + j * 16 + fr;
        bF[j] = *(const bf16x8*)((const char*)lds + sB * 16384
                   + row * 128 + ((ks ^ (row & 7)) * 16));
      }
      if (kb == 0){
        stage_tile(kt + 2);
      } else {
        if (kt < NT - 2)       asm volatile("s_waitcnt vmcnt(6)" ::: "memory");
        else if (kt == NT - 2) asm volatile("s_waitcnt vmcnt(0)" ::: "memory");
      }
      __builtin_amdgcn_s_barrier();
      __builtin_amdgcn_s_setprio(1);
      #pragma unroll
      for (int i = 0; i < 4; i++)
        #pragma unroll
        for (int j = 0; j < 4; j++)
          acc[i][j] = __builtin_amdgcn_mfma_f32_16x16x32_bf16(aF[i], bF[j], acc[i][j], 0, 0, 0);
      __builtin_amdgcn_s_setprio(0);
      __builtin_amdgcn_s_barrier();
    }
  }

  // epilogue: x = (x + y + bias) * decay
  #pragma unroll
  for (int i = 0; i < 4; i++){
    #pragma unroll
    for (int r = 0; r < 4; r++){
      const int gm = m0 + wr * 64 + i * 16 + kg * 4 + r;
      const int s = gm & (SEQ - 1);
      const float d = (((s + 1) % 10) == 0) ? 0.1f : 1.0f;
      #pragma unroll
      for (int j = 0; j < 4; j++){
        const int gn = n0 + wc * 64 + j * 16 + fr;
        const float y = acc[i][j][r] + bias[gn];
        xbuf[(size_t)gm * 512 + gn] = (xbuf[(size_t)gm * 512 + gn] + y) * d;
      }
    }
  }
}

// ---------------- MFMA GEMM 128x128, BK=64, global_load_lds + XOR-swizzled LDS ----------------
// MODE 0: x = A@B + bias0 + pos_emb                       (f32 xbuf)
// MODE 3: merged heads: n<128 frame (bias0, ld 128), else sym (bias1, ld 256); masked
template<int MODE, int K>
__global__ __launch_bounds__(256) void gemm_k(
    const short* __restrict__ A, const short* __restrict__ B,
    const float* __restrict__ bias0, const float* __restrict__ bias1,
    const float* __restrict__ pos, float* __restrict__ xbuf, short* __restrict__ obuf,
    float* __restrict__ fout, const void* __restrict__ mask, const int* __restrict__ flagp,
    int ldo)
{
  constexpr int BM = 128, BN = 128;
  __shared__ short lds[(BM + BN) * 64];
  short* lA = lds;
  short* lB = lds + BM * 64;

  const int nbx = gridDim.x;
  int bid = blockIdx.y * nbx + blockIdx.x;
  const int nwg = nbx * gridDim.y;
  bid = (bid & 7) * (nwg >> 3) + (bid >> 3);
  const int bx = bid % nbx, by = bid / nbx;
  const int n0 = bx * BN, m0 = by * BM;

  const int tid = threadIdx.x, lane = tid & 63, wid = tid >> 6;
  const int lr  = lane >> 3;
  const int lks = (lane & 7) ^ (lr & 7);
  const int fr = lane & 15;
  const int kg = lane >> 4;

  const int wr = wid >> 1, wc = wid & 1;
  const int rA0 = wr * 64 + fr;
  const int rB0 = wc * 64 + fr;

  f32x4 acc[4][4];
  const f32x4 zero = {0.f, 0.f, 0.f, 0.f};
  #pragma unroll
  for (int i = 0; i < 4; i++)
    #pragma unroll
    for (int j = 0; j < 4; j++) acc[i][j] = zero;

  const short* Ab = A + (size_t)m0 * K + (size_t)lr * K + lks * 8;
  const short* Bb = B + (size_t)n0 * K + (size_t)lr * K + lks * 8;

  for (int kt = 0; kt < K; kt += 64){
    __syncthreads();
    #pragma unroll
    for (int c = 0; c < 4; c++)
      gl_lds16(Ab + kt + (size_t)(wid + c * 4) * 8 * K, lA + (wid + c * 4) * 512);
    #pragma unroll
    for (int c = 0; c < 4; c++)
      gl_lds16(Bb + kt + (size_t)(wid + c * 4) * 8 * K, lB + (wid + c * 4) * 512);
    __syncthreads();

    #pragma unroll
    for (int kb8 = 0; kb8 < 8; kb8 += 4){
      bf16x8 aF[4], bF[4];
      #pragma unroll
      for (int i = 0; i < 4; i++){
        const int row = rA0 + i * 16;
        aF[i] = *(const bf16x8*)((const char*)lA + row * 128 + (((kg + kb8) ^ (row & 7)) * 16));
      }
      #pragma unroll
      for (int j = 0; j < 4; j++){
        const int row = rB0 + j * 16;
        bF[j] = *(const bf16x8*)((const char*)lB + row * 128 + (((kg + kb8) ^ (row & 7)) * 16));
      }
      #pragma unroll
      for (int i = 0; i < 4; i++)
        #pragma unroll
        for (int j = 0; j < 4; j++)
          acc[i][j] = __builtin_amdgcn_mfma_f32_16x16x32_bf16(aF[i], bF[j], acc[i][j], 0, 0, 0);
    }
  }

  const int col0 = n0 + wc * 64 + fr;
  const int row0 = m0 + wr * 64 + kg * 4;
  int flag = 0;
  if constexpr (MODE == 3) flag = *flagp;

  #pragma unroll
  for (int i = 0; i < 4; i++){
    #pragma unroll
    for (int r = 0; r < 4; r++){
      const int gm = row0 + i * 16 + r;
      #pragma unroll
      for (int j = 0; j < 4; j++){
        const int gn = col0 + j * 16;
        float v = acc[i][j][r];
        if constexpr (MODE == 0){
          xbuf[(size_t)gm * ldo + gn] = v + bias0[gn] + pos[(size_t)(gm & (SEQ-1)) * DMODEL + gn];
        } else {
          bool mk = mask_at(mask, flag, gm);
          if (gn < 128){
            fout[(size_t)gm * 128 + gn] = mk ? (v + bias0[gn]) : 0.0f;
          } else {
            int gs = gn - 128;
            fout[(size_t)16384 * 128 + (size_t)gm * 256 + gs] = mk ? (v + bias1[gs]) : 0.0f;
          }
        }
      }
    }
  }
}

extern "C" void kernel_launch(void* const* d_in, const int* in_sizes, int n_in,
                              void* d_out, int out_size, void* d_ws, size_t ws_size,
                              hipStream_t stream){
  const float* frames    = (const float*)d_in[0];
  const void*  mask      = d_in[1];
  const float* W_in_proj = (const float*)d_in[2];
  const float* b_in_proj = (const float*)d_in[3];
  const float* pos_emb   = (const float*)d_in[4];
  const float* ln_scale  = (const float*)d_in[5];
  const float* ln_bias   = (const float*)d_in[6];
  const float* W_in      = (const float*)d_in[7];
  const float* b_in      = (const float*)d_in[8];
  const float* W_out     = (const float*)d_in[9];
  const float* b_out     = (const float*)d_in[10];
  const float* fn_scale  = (const float*)d_in[11];
  const float* fn_bias   = (const float*)d_in[12];
  const float* W_frame   = (const float*)d_in[13];
  const float* b_frame   = (const float*)d_in[14];
  const float* W_sym     = (const float*)d_in[15];
  const float* b_sym     = (const float*)d_in[16];

  char* w = (char*)d_ws;
  int*   flag = (int*)w;
  float* xbuf = (float*)(w + 256);                                    // 16384*512 f32
  short* nbuf = (short*)(w + 256 + 33554432);                         // 16384*512 bf16
  short* abuf = (short*)(w + 256 + 33554432 + 16777216);              // 16384*1024 bf16
  short* frb  = (short*)(w + 256 + 33554432 + 16777216 + 33554432);   // 16384*128 bf16
  short* Wt0  = frb + (size_t)16384 * 128;   // [512][128]
  short* Wt1  = Wt0 + (size_t)512 * 128;     // 4x [2048][512] (u/g interleaved 16-col groups)
  short* Wt2  = Wt1 + (size_t)4 * 2048 * 512;// 4x [512][1024]
  short* Wt3  = Wt2 + (size_t)4 * 512 * 1024;// [128][512]
  short* Wt4  = Wt3 + (size_t)128 * 512;     // [256][512]  (contiguous after Wt3)

  detect_mask<<<1, 256, 0, stream>>>((const unsigned char*)mask, flag);
  cvt_bf16<<<2048, 256, 0, stream>>>(frames, frb);
  transpose_w<0><<<dim3(16,  4, 1), dim3(32, 8), 0, stream>>>(W_in_proj, Wt0, 128, 512);
  transpose_w<1><<<dim3(64, 16, 4), dim3(32, 8), 0, stream>>>(W_in,      Wt1, 512, 2048);
  transpose_w<0><<<dim3(16, 32, 4), dim3(32, 8), 0, stream>>>(W_out,     Wt2, 1024, 512);
  transpose_w<0><<<dim3(4,  16, 1), dim3(32, 8), 0, stream>>>(W_frame,   Wt3, 512, 128);
  transpose_w<0><<<dim3(8,  16, 1), dim3(32, 8), 0, stream>>>(W_sym,     Wt4, 512, 256);

  gemm_k<0, 128><<<dim3(4, 128), 256, 0, stream>>>(frb, Wt0, b_in_proj, nullptr, pos_emb,
      xbuf, nullptr, nullptr, nullptr, nullptr, 512);

  for (int l = 0; l < 4; l++){
    ln_k<<<4096, 256, 0, stream>>>(xbuf, ln_scale + l*512, ln_bias + l*512, nbuf);
    glu8p<512><<<dim3(8, 64), 512, 0, stream>>>(nbuf,
        Wt1 + (size_t)l*2048*512, b_in + l*2048, abuf);
    res8p<1024><<<dim3(2, 128), 512, 0, stream>>>(abuf, Wt2 + (size_t)l*512*1024,
        b_out + l*512, xbuf);
  }

  ln_k<<<4096, 256, 0, stream>>>(xbuf, fn_scale, fn_bias, nbuf);
  gemm_k<3, 512><<<dim3(3, 128), 256, 0, stream>>>(nbuf, Wt3, b_frame, b_sym, nullptr,
      nullptr, nullptr, (float*)d_out, mask, flag, 0);
}

// Round 8
// 514.204 us; speedup vs baseline: 1.5308x; 1.0099x over previous
//
#include <hip/hip_runtime.h>
#include <hip/hip_bf16.h>

using f32x4  = __attribute__((ext_vector_type(4))) float;
using bf16x8 = __attribute__((ext_vector_type(8))) short;
using bf16x4 = __attribute__((ext_vector_type(4))) short;

#define SEQ 2048

__device__ __forceinline__ short f2b(float f){
  unsigned u = __builtin_bit_cast(unsigned, f);
  u = (u + 0x7FFFu + ((u >> 16) & 1u)) >> 16;   // RNE
  return (short)u;
}

__device__ __forceinline__ void gl_lds16(const short* g, short* l){
  __builtin_amdgcn_global_load_lds(
      (const __attribute__((address_space(1))) void*)g,
      (__attribute__((address_space(3))) void*)l, 16, 0, 0);
}

__device__ __forceinline__ bool mask_at(const void* mask, int flag, int m){
  if (flag == 1) return ((const unsigned char*)mask)[m] != 0;
  if (flag == 2) return ((const float*)mask)[m] != 0.0f;
  if (flag == 3) return ((const int*)mask)[2*m] != 0;
  return ((const int*)mask)[m] != 0;
}

// ================= prep: fused frames-cvt + 5 weight transposes + mask detect =================
__device__ __forceinline__ void tr32(float (*t)[33], const float* in, short* out,
                                     int R, int C, int bx, int by, int z, int glu){
  in  += (size_t)z * R * C;
  out += (size_t)z * R * C;
  int tx = threadIdx.x & 31, ty = threadIdx.x >> 5;
  int r0 = by * 32, c0 = bx * 32;
  #pragma unroll
  for (int i = 0; i < 4; i++)
    t[ty + i*8][tx] = in[(size_t)(r0 + ty + i*8) * C + c0 + tx];
  __syncthreads();
  #pragma unroll
  for (int i = 0; i < 4; i++){
    int oc = c0 + ty + i*8;
    int nr = oc;
    if (glu){
      int half = C >> 1;
      nr = (oc < half) ? (((oc >> 4) << 5) + (oc & 15))
                       : ((((oc - half) >> 4) << 5) + 16 + (oc & 15));
    }
    out[(size_t)nr * R + r0 + tx] = f2b(t[tx][ty + i*8]);
  }
}

__global__ __launch_bounds__(256) void prep(
    const float* __restrict__ frames, short* __restrict__ frb,
    const float* __restrict__ Wip, short* __restrict__ Wt0,
    const float* __restrict__ Win, short* __restrict__ Wt1,
    const float* __restrict__ Wout, short* __restrict__ Wt2,
    const float* __restrict__ Wfr, short* __restrict__ Wt3,
    const float* __restrict__ Wsy, short* __restrict__ Wt4,
    const unsigned char* __restrict__ mask, int* __restrict__ flag)
{
  __shared__ float t[32][33];
  const int b = blockIdx.x;
  if (b < 2048){
    int i = (b * 256 + threadIdx.x) * 4;
    float4 v = *(const float4*)(frames + i);
    bf16x4 o; o[0]=f2b(v.x); o[1]=f2b(v.y); o[2]=f2b(v.z); o[3]=f2b(v.w);
    *(bf16x4*)(frb + i) = o;
  } else if (b < 2112){
    int L = b - 2048; tr32(t, Wip, Wt0, 128, 512, L % 16, L / 16, 0, 0);
  } else if (b < 6208){
    int L = b - 2112; tr32(t, Win, Wt1, 512, 2048, L % 64, (L / 64) % 16, L / 1024, 1);
  } else if (b < 8256){
    int L = b - 6208; tr32(t, Wout, Wt2, 1024, 512, L % 16, (L / 16) % 32, L / 512, 0);
  } else if (b < 8320){
    int L = b - 8256; tr32(t, Wfr, Wt3, 512, 128, L % 4, L / 4, 0, 0);
  } else if (b < 8448){
    int L = b - 8320; tr32(t, Wsy, Wt4, 512, 256, L % 8, L / 8, 0, 0);
  } else {
    int* si = (int*)t;
    int tid = threadIdx.x;
    if (tid < 3) si[tid] = 0;
    __syncthreads();
    int ge2 = 0, off = 0, off8 = 0;
    for (int i = tid; i < 16384; i += 256){
      unsigned char c = mask[i];
      if (c >= 2) ge2++;
      if ((i & 3) && c) off++;
      if (((i & 7) == 4) && c) off8++;
    }
    atomicAdd(&si[0], ge2); atomicAdd(&si[1], off); atomicAdd(&si[2], off8);
    __syncthreads();
    if (tid == 0){
      int f;
      if      (si[0] > 0) f = 2;   // float32
      else if (si[1] > 0) f = 1;   // bool/u8
      else if (si[2] > 0) f = 0;   // int32
      else                f = 3;   // int64
      *flag = f;
    }
  }
}

// ================= GLU 256x256 8-phase MFMA GEMM (T2+T3+T4+T5) =================
// Half order per K-tile: [Bh0, Bh1, Ah0, Ah1]; slot = h&7; staged at distance 5
// (race-free: restage of any slot issues >=1 barrier after its last read).
// Counted vmcnt(2) once per K-tile; vmcnt(0) only at drain.
template<int K>
__global__ __launch_bounds__(512, 2) void glu8p(
    const short* __restrict__ A, const short* __restrict__ B,
    const float* __restrict__ bias, short* __restrict__ obuf)
{
  constexpr int NT = K / 64;
  constexpr int HT = NT * 4;
  __shared__ short lds[8 * 8192];   // 128 KiB

  const int nbx = gridDim.x;
  int bid = blockIdx.y * nbx + blockIdx.x;
  const int nwg = nbx * gridDim.y;
  bid = (bid & 7) * (nwg >> 3) + (bid >> 3);   // bijective XCD swizzle (nwg%8==0)
  const int n0 = (bid % nbx) * 256, m0 = (bid / nbx) * 256;

  const int tid = threadIdx.x, lane = tid & 63, wid = tid >> 6;
  const int wr = wid >> 2, wc = wid & 3;       // wave grid 2M x 4N
  const int fr = lane & 15, kg = lane >> 4;

  f32x4 acc[8][2][2];
  const f32x4 zero = {0.f, 0.f, 0.f, 0.f};
  #pragma unroll
  for (int i = 0; i < 8; i++)
    #pragma unroll
    for (int nh = 0; nh < 2; nh++)
      #pragma unroll
      for (int j = 0; j < 2; j++) acc[i][nh][j] = zero;

  const int rl0 = wid * 8 + (lane >> 3);
  const int swz = ((lane & 7) ^ ((lane >> 3) & 7)) * 8;
  const short* Ab = A + ((size_t)m0 + rl0) * K + swz;
  const short* Bb = B + ((size_t)n0 + rl0) * K + swz;

  auto stage = [&](int h){
    if (h < HT){
      const int q = h & 3, kt2 = h >> 2, slot = h & 7;
      const short* src = (q < 2) ? (Bb + (size_t)(q * 128) * K + kt2 * 64)
                                 : (Ab + (size_t)((q - 2) * 128) * K + kt2 * 64);
      short* dst = lds + slot * 8192 + wid * 512;
      gl_lds16(src, dst);
      gl_lds16(src + (size_t)64 * K, dst + 4096);
    }
  };

  #pragma unroll
  for (int h = 0; h < 5; h++) stage(h);
  asm volatile("s_waitcnt vmcnt(2)" ::: "memory");
  __builtin_amdgcn_s_barrier();

  for (int kt = 0; kt < NT; ++kt){
    bf16x8 aF[8];
    #pragma unroll
    for (int p = 0; p < 4; ++p){
      const int kb = p >> 1, nh = p & 1;
      const int ks = kg + kb * 4;
      if (nh == 0){
        const int slot = (4 * kt + 2 + wr) & 7;
        #pragma unroll
        for (int i = 0; i < 8; i++)
          aF[i] = *(const bf16x8*)((const char*)lds + slot * 16384
                     + (i * 16 + fr) * 128 + ((ks ^ (fr & 7)) * 16));
      }
      bf16x8 bF[2];
      {
        const int slot = (4 * kt + nh) & 7;
        #pragma unroll
        for (int j = 0; j < 2; j++)
          bF[j] = *(const bf16x8*)((const char*)lds + slot * 16384
                     + (wc * 32 + j * 16 + fr) * 128 + ((ks ^ (fr & 7)) * 16));
      }
      stage(4 * kt + p + 5);
      if (p == 3){
        if (kt < NT - 2)       asm volatile("s_waitcnt vmcnt(2)" ::: "memory");
        else if (kt == NT - 2) asm volatile("s_waitcnt vmcnt(0)" ::: "memory");
      }
      __builtin_amdgcn_s_barrier();
      __builtin_amdgcn_s_setprio(1);
      #pragma unroll
      for (int i = 0; i < 8; i++)
        #pragma unroll
        for (int j = 0; j < 2; j++)
          acc[i][nh][j] = __builtin_amdgcn_mfma_f32_16x16x32_bf16(aF[i], bF[j], acc[i][nh][j], 0, 0, 0);
      __builtin_amdgcn_s_setprio(0);
      __builtin_amdgcn_s_barrier();
    }
  }

  // epilogue: frag j=0 is u (cols 32c+0..15), j=1 is g (cols 32c+16..31)
  #pragma unroll
  for (int i = 0; i < 8; i++){
    #pragma unroll
    for (int nh = 0; nh < 2; nh++){
      const int pc = n0 + nh * 128 + wc * 32;
      const int lc = ((pc >> 5) << 4) + fr;
      #pragma unroll
      for (int r = 0; r < 4; r++){
        const int gm = m0 + wr * 128 + i * 16 + kg * 4 + r;
        float u = acc[i][nh][0][r] + bias[lc];
        float g = acc[i][nh][1][r] + bias[1024 + lc];
        float sg = g / (1.0f + expf(-g));
        obuf[(size_t)gm * 1024 + lc] = f2b(u * sg);
      }
    }
  }
}

// ================= residual GEMM + fused LayerNorm, BM=64 x BN=512 =================
// 8 waves (1M x 8N, wave 64x64), BK=64. Units of 8KB: [A, B0..B7] per K-tile;
// double-buffer 18 units = 144 KiB. Stage tile kt+1 at kb0; vmcnt(0) at kb1.
// Epilogue: x = (x + y + bias)*decay -> row LN (shfl + LDS reduce) -> xbuf f32 + nbuf bf16.
template<int K>
__global__ __launch_bounds__(512, 2) void res8p(
    const short* __restrict__ A, const short* __restrict__ B,
    const float* __restrict__ bias,
    const float* __restrict__ sc, const float* __restrict__ bi,
    float* __restrict__ xbuf, short* __restrict__ nbuf)
{
  constexpr int NT = K / 64;          // 16
  __shared__ short lds[18 * 4096];    // 147456 B

  int bid = blockIdx.x;
  const int nwg = gridDim.x;
  bid = (bid & 7) * (nwg >> 3) + (bid >> 3);
  const int m0 = bid * 64;

  const int tid = threadIdx.x, lane = tid & 63, wid = tid >> 6;
  const int fr = lane & 15, kg = lane >> 4;

  f32x4 acc[4][4];
  const f32x4 zero = {0.f, 0.f, 0.f, 0.f};
  #pragma unroll
  for (int i = 0; i < 4; i++)
    #pragma unroll
    for (int j = 0; j < 4; j++) acc[i][j] = zero;

  const int rl0 = tid >> 3;                       // 0..63
  const int swz = ((tid & 7) ^ (rl0 & 7)) * 8;
  const short* Ab = A + ((size_t)m0 + rl0) * K + swz;
  const short* Bb = B + (size_t)rl0 * K + swz;

  auto stageT = [&](int t){
    if (t < NT){
      short* wb = lds + (t & 1) * 36864 + wid * 512;
      gl_lds16(Ab + t * 64, wb);
      #pragma unroll
      for (int u = 0; u < 8; u++)
        gl_lds16(Bb + (size_t)(u * 64) * K + t * 64, wb + (1 + u) * 4096);
    }
  };

  stageT(0);
  asm volatile("s_waitcnt vmcnt(0)" ::: "memory");
  __builtin_amdgcn_s_barrier();

  for (int kt = 0; kt < NT; ++kt){
    const char* buf = (const char*)lds + (kt & 1) * 73728;
    #pragma unroll
    for (int kb = 0; kb < 2; kb++){
      const int ks = kg + kb * 4;
      bf16x8 aF[4], bF[4];
      #pragma unroll
      for (int i = 0; i < 4; i++){
        const int row = i * 16 + fr;
        aF[i] = *(const bf16x8*)(buf + row * 128 + ((ks ^ (row & 7)) * 16));
      }
      #pragma unroll
      for (int j = 0; j < 4; j++){
        const int row = j * 16 + fr;
        bF[j] = *(const bf16x8*)(buf + (1 + wid) * 8192 + row * 128 + ((ks ^ (row & 7)) * 16));
      }
      if (kb == 0) stageT(kt + 1);
      else asm volatile("s_waitcnt vmcnt(0)" ::: "memory");
      __builtin_amdgcn_s_barrier();
      __builtin_amdgcn_s_setprio(1);
      #pragma unroll
      for (int i = 0; i < 4; i++)
        #pragma unroll
        for (int j = 0; j < 4; j++)
          acc[i][j] = __builtin_amdgcn_mfma_f32_16x16x32_bf16(aF[i], bF[j], acc[i][j], 0, 0, 0);
      __builtin_amdgcn_s_setprio(0);
      __builtin_amdgcn_s_barrier();
    }
  }

  // ---- epilogue: residual + decay (in-place in acc) ----
  #pragma unroll
  for (int i = 0; i < 4; i++){
    #pragma unroll
    for (int r = 0; r < 4; r++){
      const int row = i * 16 + kg * 4 + r;
      const int gm = m0 + row;
      const float d = ((((gm & (SEQ-1)) + 1) % 10) == 0) ? 0.1f : 1.0f;
      #pragma unroll
      for (int j = 0; j < 4; j++){
        const int gn = wid * 64 + j * 16 + fr;
        const float xo = xbuf[(size_t)gm * 512 + gn];
        acc[i][j][r] = (xo + acc[i][j][r] + bias[gn]) * d;
      }
    }
  }
  // ---- fused LayerNorm over the full 512-wide row ----
  float* fs = (float*)lds;
  __syncthreads();   // drain in-flight ds_reads before reusing staging LDS as scratch
  #pragma unroll
  for (int i = 0; i < 4; i++){
    #pragma unroll
    for (int r = 0; r < 4; r++){
      float s = acc[i][0][r] + acc[i][1][r] + acc[i][2][r] + acc[i][3][r];
      float q = acc[i][0][r]*acc[i][0][r] + acc[i][1][r]*acc[i][1][r]
              + acc[i][2][r]*acc[i][2][r] + acc[i][3][r]*acc[i][3][r];
      #pragma unroll
      for (int o = 1; o < 16; o <<= 1){ s += __shfl_xor(s, o); q += __shfl_xor(q, o); }
      if (fr == 0){
        const int row = i * 16 + kg * 4 + r;
        fs[wid * 64 + row]       = s;
        fs[512 + wid * 64 + row] = q;
      }
    }
  }
  __syncthreads();
  if (tid < 64){
    float s = 0.f, q = 0.f;
    #pragma unroll
    for (int w8 = 0; w8 < 8; w8++){ s += fs[w8 * 64 + tid]; q += fs[512 + w8 * 64 + tid]; }
    const float mu = s * (1.0f / 512.0f);
    const float var = q * (1.0f / 512.0f) - mu * mu;
    fs[1024 + tid] = mu;
    fs[1088 + tid] = rsqrtf(var + 1e-5f);
  }
  __syncthreads();
  #pragma unroll
  for (int i = 0; i < 4; i++){
    #pragma unroll
    for (int r = 0; r < 4; r++){
      const int row = i * 16 + kg * 4 + r;
      const int gm = m0 + row;
      const float mu = fs[1024 + row], rs = fs[1088 + row];
      #pragma unroll
      for (int j = 0; j < 4; j++){
        const int gn = wid * 64 + j * 16 + fr;
        const float v = acc[i][j][r];
        xbuf[(size_t)gm * 512 + gn] = v;
        nbuf[(size_t)gm * 512 + gn] = f2b((v - mu) * rs * sc[gn] + bi[gn]);
      }
    }
  }
}

// ================= input projection + pos_emb + fused LN0, BM=64 x BN=512, K=128 =================
__global__ __launch_bounds__(512, 2) void in0ln(
    const short* __restrict__ A, const short* __restrict__ B,
    const float* __restrict__ bias, const float* __restrict__ pos,
    const float* __restrict__ sc, const float* __restrict__ bi,
    float* __restrict__ xbuf, short* __restrict__ nbuf)
{
  constexpr int K = 128;
  __shared__ short lds[18 * 4096];

  int bid = blockIdx.x;
  const int nwg = gridDim.x;
  bid = (bid & 7) * (nwg >> 3) + (bid >> 3);
  const int m0 = bid * 64;

  const int tid = threadIdx.x, lane = tid & 63, wid = tid >> 6;
  const int fr = lane & 15, kg = lane >> 4;

  f32x4 acc[4][4];
  const f32x4 zero = {0.f, 0.f, 0.f, 0.f};
  #pragma unroll
  for (int i = 0; i < 4; i++)
    #pragma unroll
    for (int j = 0; j < 4; j++) acc[i][j] = zero;

  const int rl0 = tid >> 3;
  const int swz = ((tid & 7) ^ (rl0 & 7)) * 8;
  const short* Ab = A + ((size_t)m0 + rl0) * K + swz;
  const short* Bb = B + (size_t)rl0 * K + swz;

  #pragma unroll
  for (int t = 0; t < 2; t++){
    short* wb = lds + t * 36864 + wid * 512;
    gl_lds16(Ab + t * 64, wb);
    #pragma unroll
    for (int u = 0; u < 8; u++)
      gl_lds16(Bb + (size_t)(u * 64) * K + t * 64, wb + (1 + u) * 4096);
  }
  asm volatile("s_waitcnt vmcnt(0)" ::: "memory");
  __builtin_amdgcn_s_barrier();

  #pragma unroll
  for (int kt = 0; kt < 2; ++kt){
    const char* buf = (const char*)lds + kt * 73728;
    #pragma unroll
    for (int kb = 0; kb < 2; kb++){
      const int ks = kg + kb * 4;
      bf16x8 aF[4], bF[4];
      #pragma unroll
      for (int i = 0; i < 4; i++){
        const int row = i * 16 + fr;
        aF[i] = *(const bf16x8*)(buf + row * 128 + ((ks ^ (row & 7)) * 16));
      }
      #pragma unroll
      for (int j = 0; j < 4; j++){
        const int row = j * 16 + fr;
        bF[j] = *(const bf16x8*)(buf + (1 + wid) * 8192 + row * 128 + ((ks ^ (row & 7)) * 16));
      }
      #pragma unroll
      for (int i = 0; i < 4; i++)
        #pragma unroll
        for (int j = 0; j < 4; j++)
          acc[i][j] = __builtin_amdgcn_mfma_f32_16x16x32_bf16(aF[i], bF[j], acc[i][j], 0, 0, 0);
    }
  }

  // epilogue: + bias + pos_emb, then fused LN (ln_scale[0]/ln_bias[0])
  #pragma unroll
  for (int i = 0; i < 4; i++){
    #pragma unroll
    for (int r = 0; r < 4; r++){
      const int row = i * 16 + kg * 4 + r;
      const int gm = m0 + row;
      #pragma unroll
      for (int j = 0; j < 4; j++){
        const int gn = wid * 64 + j * 16 + fr;
        acc[i][j][r] += bias[gn] + pos[(size_t)(gm & (SEQ-1)) * 512 + gn];
      }
    }
  }
  float* fs = (float*)lds;
  __syncthreads();
  #pragma unroll
  for (int i = 0; i < 4; i++){
    #pragma unroll
    for (int r = 0; r < 4; r++){
      float s = acc[i][0][r] + acc[i][1][r] + acc[i][2][r] + acc[i][3][r];
      float q = acc[i][0][r]*acc[i][0][r] + acc[i][1][r]*acc[i][1][r]
              + acc[i][2][r]*acc[i][2][r] + acc[i][3][r]*acc[i][3][r];
      #pragma unroll
      for (int o = 1; o < 16; o <<= 1){ s += __shfl_xor(s, o); q += __shfl_xor(q, o); }
      if (fr == 0){
        const int row = i * 16 + kg * 4 + r;
        fs[wid * 64 + row]       = s;
        fs[512 + wid * 64 + row] = q;
      }
    }
  }
  __syncthreads();
  if (tid < 64){
    float s = 0.f, q = 0.f;
    #pragma unroll
    for (int w8 = 0; w8 < 8; w8++){ s += fs[w8 * 64 + tid]; q += fs[512 + w8 * 64 + tid]; }
    const float mu = s * (1.0f / 512.0f);
    const float var = q * (1.0f / 512.0f) - mu * mu;
    fs[1024 + tid] = mu;
    fs[1088 + tid] = rsqrtf(var + 1e-5f);
  }
  __syncthreads();
  #pragma unroll
  for (int i = 0; i < 4; i++){
    #pragma unroll
    for (int r = 0; r < 4; r++){
      const int row = i * 16 + kg * 4 + r;
      const int gm = m0 + row;
      const float mu = fs[1024 + row], rs = fs[1088 + row];
      #pragma unroll
      for (int j = 0; j < 4; j++){
        const int gn = wid * 64 + j * 16 + fr;
        const float v = acc[i][j][r];
        xbuf[(size_t)gm * 512 + gn] = v;
        nbuf[(size_t)gm * 512 + gn] = f2b((v - mu) * rs * sc[gn] + bi[gn]);
      }
    }
  }
}

// ================= merged heads GEMM (128x128, K=512), masked =================
__global__ __launch_bounds__(256) void heads_k(
    const short* __restrict__ A, const short* __restrict__ B,
    const float* __restrict__ bias0, const float* __restrict__ bias1,
    float* __restrict__ fout, const void* __restrict__ mask, const int* __restrict__ flagp)
{
  constexpr int K = 512, BM = 128, BN = 128;
  __shared__ short lds[(BM + BN) * 64];
  short* lA = lds;
  short* lB = lds + BM * 64;

  const int nbx = gridDim.x;
  int bid = blockIdx.y * nbx + blockIdx.x;
  const int nwg = nbx * gridDim.y;
  bid = (bid & 7) * (nwg >> 3) + (bid >> 3);
  const int n0 = (bid % nbx) * BN, m0 = (bid / nbx) * BM;

  const int tid = threadIdx.x, lane = tid & 63, wid = tid >> 6;
  const int lr  = lane >> 3;
  const int lks = (lane & 7) ^ (lr & 7);
  const int fr = lane & 15;
  const int kg = lane >> 4;

  const int wr = wid >> 1, wc = wid & 1;
  const int rA0 = wr * 64 + fr;
  const int rB0 = wc * 64 + fr;

  f32x4 acc[4][4];
  const f32x4 zero = {0.f, 0.f, 0.f, 0.f};
  #pragma unroll
  for (int i = 0; i < 4; i++)
    #pragma unroll
    for (int j = 0; j < 4; j++) acc[i][j] = zero;

  const short* Ab = A + (size_t)m0 * K + (size_t)lr * K + lks * 8;
  const short* Bb = B + (size_t)n0 * K + (size_t)lr * K + lks * 8;

  for (int kt = 0; kt < K; kt += 64){
    __syncthreads();
    #pragma unroll
    for (int c = 0; c < 4; c++)
      gl_lds16(Ab + kt + (size_t)(wid + c * 4) * 8 * K, lA + (wid + c * 4) * 512);
    #pragma unroll
    for (int c = 0; c < 4; c++)
      gl_lds16(Bb + kt + (size_t)(wid + c * 4) * 8 * K, lB + (wid + c * 4) * 512);
    __syncthreads();

    #pragma unroll
    for (int kb8 = 0; kb8 < 8; kb8 += 4){
      bf16x8 aF[4], bF[4];
      #pragma unroll
      for (int i = 0; i < 4; i++){
        const int row = rA0 + i * 16;
        aF[i] = *(const bf16x8*)((const char*)lA + row * 128 + (((kg + kb8) ^ (row & 7)) * 16));
      }
      #pragma unroll
      for (int j = 0; j < 4; j++){
        const int row = rB0 + j * 16;
        bF[j] = *(const bf16x8*)((const char*)lB + row * 128 + (((kg + kb8) ^ (row & 7)) * 16));
      }
      #pragma unroll
      for (int i = 0; i < 4; i++)
        #pragma unroll
        for (int j = 0; j < 4; j++)
          acc[i][j] = __builtin_amdgcn_mfma_f32_16x16x32_bf16(aF[i], bF[j], acc[i][j], 0, 0, 0);
    }
  }

  const int col0 = n0 + wc * 64 + fr;
  const int row0 = m0 + wr * 64 + kg * 4;
  const int flag = *flagp;

  #pragma unroll
  for (int i = 0; i < 4; i++){
    #pragma unroll
    for (int r = 0; r < 4; r++){
      const int gm = row0 + i * 16 + r;
      const bool mk = mask_at(mask, flag, gm);
      #pragma unroll
      for (int j = 0; j < 4; j++){
        const int gn = col0 + j * 16;
        const float v = acc[i][j][r];
        if (gn < 128){
          fout[(size_t)gm * 128 + gn] = mk ? (v + bias0[gn]) : 0.0f;
        } else {
          const int gs = gn - 128;
          fout[(size_t)16384 * 128 + (size_t)gm * 256 + gs] = mk ? (v + bias1[gs]) : 0.0f;
        }
      }
    }
  }
}

extern "C" void kernel_launch(void* const* d_in, const int* in_sizes, int n_in,
                              void* d_out, int out_size, void* d_ws, size_t ws_size,
                              hipStream_t stream){
  const float* frames    = (const float*)d_in[0];
  const void*  mask      = d_in[1];
  const float* W_in_proj = (const float*)d_in[2];
  const float* b_in_proj = (const float*)d_in[3];
  const float* pos_emb   = (const float*)d_in[4];
  const float* ln_scale  = (const float*)d_in[5];
  const float* ln_bias   = (const float*)d_in[6];
  const float* W_in      = (const float*)d_in[7];
  const float* b_in      = (const float*)d_in[8];
  const float* W_out     = (const float*)d_in[9];
  const float* b_out     = (const float*)d_in[10];
  const float* fn_scale  = (const float*)d_in[11];
  const float* fn_bias   = (const float*)d_in[12];
  const float* W_frame   = (const float*)d_in[13];
  const float* b_frame   = (const float*)d_in[14];
  const float* W_sym     = (const float*)d_in[15];
  const float* b_sym     = (const float*)d_in[16];

  char* w = (char*)d_ws;
  int*   flag = (int*)w;
  float* xbuf = (float*)(w + 256);                                    // 16384*512 f32
  short* nbuf = (short*)(w + 256 + 33554432);                         // 16384*512 bf16
  short* abuf = (short*)(w + 256 + 33554432 + 16777216);              // 16384*1024 bf16
  short* frb  = (short*)(w + 256 + 33554432 + 16777216 + 33554432);   // 16384*128 bf16
  short* Wt0  = frb + (size_t)16384 * 128;   // [512][128]
  short* Wt1  = Wt0 + (size_t)512 * 128;     // 4x [2048][512] (u/g interleaved)
  short* Wt2  = Wt1 + (size_t)4 * 2048 * 512;// 4x [512][1024]
  short* Wt3  = Wt2 + (size_t)4 * 512 * 1024;// [128][512]
  short* Wt4  = Wt3 + (size_t)128 * 512;     // [256][512]

  prep<<<8449, 256, 0, stream>>>(frames, frb, W_in_proj, Wt0, W_in, Wt1, W_out, Wt2,
                                 W_frame, Wt3, W_sym, Wt4, (const unsigned char*)mask, flag);

  in0ln<<<256, 512, 0, stream>>>(frb, Wt0, b_in_proj, pos_emb, ln_scale, ln_bias, xbuf, nbuf);

  for (int l = 0; l < 4; l++){
    glu8p<512><<<dim3(8, 64), 512, 0, stream>>>(nbuf,
        Wt1 + (size_t)l * 2048 * 512, b_in + l * 2048, abuf);
    const float* s2 = (l < 3) ? (ln_scale + (l + 1) * 512) : fn_scale;
    const float* b2 = (l < 3) ? (ln_bias  + (l + 1) * 512) : fn_bias;
    res8p<1024><<<256, 512, 0, stream>>>(abuf, Wt2 + (size_t)l * 512 * 1024,
        b_out + l * 512, s2, b2, xbuf, nbuf);
  }

  heads_k<<<dim3(3, 128), 256, 0, stream>>>(nbuf, Wt3, b_frame, b_sym,
      (float*)d_out, mask, flag);
}

// Round 9
// 510.212 us; speedup vs baseline: 1.5427x; 1.0078x over previous
//
#include <hip/hip_runtime.h>
#include <hip/hip_bf16.h>

using f32x4  = __attribute__((ext_vector_type(4))) float;
using bf16x8 = __attribute__((ext_vector_type(8))) short;
using bf16x4 = __attribute__((ext_vector_type(4))) short;

#define SEQ 2048

__device__ __forceinline__ short f2b(float f){
  unsigned u = __builtin_bit_cast(unsigned, f);
  u = (u + 0x7FFFu + ((u >> 16) & 1u)) >> 16;   // RNE
  return (short)u;
}

__device__ __forceinline__ void gl_lds16(const short* g, short* l){
  __builtin_amdgcn_global_load_lds(
      (const __attribute__((address_space(1))) void*)g,
      (__attribute__((address_space(3))) void*)l, 16, 0, 0);
}

__device__ __forceinline__ bool mask_at(const void* mask, int flag, int m){
  if (flag == 1) return ((const unsigned char*)mask)[m] != 0;
  if (flag == 2) return ((const float*)mask)[m] != 0.0f;
  if (flag == 3) return ((const int*)mask)[2*m] != 0;
  return ((const int*)mask)[m] != 0;
}

// ================= prep: fused frames-cvt + 5 weight transposes + mask detect =================
__device__ __forceinline__ void tr32(float (*t)[33], const float* in, short* out,
                                     int R, int C, int bx, int by, int z, int glu){
  in  += (size_t)z * R * C;
  out += (size_t)z * R * C;
  int tx = threadIdx.x & 31, ty = threadIdx.x >> 5;
  int r0 = by * 32, c0 = bx * 32;
  #pragma unroll
  for (int i = 0; i < 4; i++)
    t[ty + i*8][tx] = in[(size_t)(r0 + ty + i*8) * C + c0 + tx];
  __syncthreads();
  #pragma unroll
  for (int i = 0; i < 4; i++){
    int oc = c0 + ty + i*8;
    int nr = oc;
    if (glu){
      int half = C >> 1;
      nr = (oc < half) ? (((oc >> 4) << 5) + (oc & 15))
                       : ((((oc - half) >> 4) << 5) + 16 + (oc & 15));
    }
    out[(size_t)nr * R + r0 + tx] = f2b(t[tx][ty + i*8]);
  }
}

__global__ __launch_bounds__(256) void prep(
    const float* __restrict__ frames, short* __restrict__ frb,
    const float* __restrict__ Wip, short* __restrict__ Wt0,
    const float* __restrict__ Win, short* __restrict__ Wt1,
    const float* __restrict__ Wout, short* __restrict__ Wt2,
    const float* __restrict__ Wfr, short* __restrict__ Wt3,
    const float* __restrict__ Wsy, short* __restrict__ Wt4,
    const unsigned char* __restrict__ mask, int* __restrict__ flag)
{
  __shared__ float t[32][33];
  const int b = blockIdx.x;
  if (b < 2048){
    int i = (b * 256 + threadIdx.x) * 4;
    float4 v = *(const float4*)(frames + i);
    bf16x4 o; o[0]=f2b(v.x); o[1]=f2b(v.y); o[2]=f2b(v.z); o[3]=f2b(v.w);
    *(bf16x4*)(frb + i) = o;
  } else if (b < 2112){
    int L = b - 2048; tr32(t, Wip, Wt0, 128, 512, L % 16, L / 16, 0, 0);
  } else if (b < 6208){
    int L = b - 2112; tr32(t, Win, Wt1, 512, 2048, L % 64, (L / 64) % 16, L / 1024, 1);
  } else if (b < 8256){
    int L = b - 6208; tr32(t, Wout, Wt2, 1024, 512, L % 16, (L / 16) % 32, L / 512, 0);
  } else if (b < 8320){
    int L = b - 8256; tr32(t, Wfr, Wt3, 512, 128, L % 4, L / 4, 0, 0);
  } else if (b < 8448){
    int L = b - 8320; tr32(t, Wsy, Wt4, 512, 256, L % 8, L / 8, 0, 0);
  } else {
    int* si = (int*)t;
    int tid = threadIdx.x;
    if (tid < 3) si[tid] = 0;
    __syncthreads();
    int ge2 = 0, off = 0, off8 = 0;
    for (int i = tid; i < 16384; i += 256){
      unsigned char c = mask[i];
      if (c >= 2) ge2++;
      if ((i & 3) && c) off++;
      if (((i & 7) == 4) && c) off8++;
    }
    atomicAdd(&si[0], ge2); atomicAdd(&si[1], off); atomicAdd(&si[2], off8);
    __syncthreads();
    if (tid == 0){
      int f;
      if      (si[0] > 0) f = 2;   // float32
      else if (si[1] > 0) f = 1;   // bool/u8
      else if (si[2] > 0) f = 0;   // int32
      else                f = 3;   // int64
      *flag = f;
    }
  }
}

// ================= GLU 256x256 8-phase MFMA GEMM, 9-slot ring, depth-7 prefetch =================
// Halves per K-tile: [A0, A1, B0, B1]; slot = h mod 9 (wrapping counters, no modulo).
// Phases p = (nh,kb): (0,0),(0,1),(1,0),(1,1); two live A-frag sets (aF0=kb0, aF1=kb1)
// so every slot's last read is p1 (A0,A1,B0) or p3 (B1) -> ring-9 at distance 7 gives
// >=1 barrier between last read and restage issue (verified per-slot). Counted vmcnt(6)
// once per K-tile at p3 (after the stage issue!); vmcnt(0) only at the drain (kt==NT-2).
template<int K>
__global__ __launch_bounds__(512, 2) void glu8p(
    const short* __restrict__ A, const short* __restrict__ B,
    const float* __restrict__ bias, short* __restrict__ obuf)
{
  constexpr int NT = K / 64;
  constexpr int HT = NT * 4;
  __shared__ short lds[9 * 8192];   // 144 KiB, 9 x 16KB half-tile slots

  const int nbx = gridDim.x;
  int bid = blockIdx.y * nbx + blockIdx.x;
  const int nwg = nbx * gridDim.y;
  bid = (bid & 7) * (nwg >> 3) + (bid >> 3);   // bijective XCD swizzle (nwg%8==0)
  const int n0 = (bid % nbx) * 256, m0 = (bid / nbx) * 256;

  const int tid = threadIdx.x, lane = tid & 63, wid = tid >> 6;
  const int wr = wid >> 2, wc = wid & 3;       // wave grid 2M x 4N
  const int fr = lane & 15, kg = lane >> 4;

  f32x4 acc[8][2][2];
  const f32x4 zero = {0.f, 0.f, 0.f, 0.f};
  #pragma unroll
  for (int i = 0; i < 8; i++)
    #pragma unroll
    for (int nh = 0; nh < 2; nh++)
      #pragma unroll
      for (int j = 0; j < 2; j++) acc[i][nh][j] = zero;

  const int rl0 = wid * 8 + (lane >> 3);
  const int swz = ((lane & 7) ^ ((lane >> 3) & 7)) * 8;
  const short* Ab = A + ((size_t)m0 + rl0) * K + swz;
  const short* Bb = B + ((size_t)n0 + rl0) * K + swz;

  auto stage = [&](int h, int slot){
    if (h < HT){
      const int q = h & 3, kt2 = h >> 2;
      const short* src = (q < 2) ? (Ab + (size_t)(q * 128) * K + kt2 * 64)
                                 : (Bb + (size_t)((q - 2) * 128) * K + kt2 * 64);
      short* dst = lds + slot * 8192 + wid * 512;
      gl_lds16(src, dst);
      gl_lds16(src + (size_t)64 * K, dst + 4096);
    }
  };

  int ss = 0;
  #pragma unroll
  for (int h = 0; h < 7; h++){ stage(h, ss); ss++; }   // ss = 7
  asm volatile("s_waitcnt vmcnt(6)" ::: "memory");      // tile 0 (4 halves) landed
  __builtin_amdgcn_s_barrier();

  int rb = 0;   // slot of half 4*kt
  for (int kt = 0; kt < NT; ++kt){
    int sA = rb + wr;  if (sA >= 9) sA -= 9;
    int sB0 = rb + 2;  if (sB0 >= 9) sB0 -= 9;
    int sB1 = rb + 3;  if (sB1 >= 9) sB1 -= 9;
    bf16x8 aF0[8], aF1[8];
    #pragma unroll
    for (int p = 0; p < 4; ++p){
      const int nh = p >> 1, kb = p & 1;
      const int ks = kg + kb * 4;
      if (p == 0){
        #pragma unroll
        for (int i = 0; i < 8; i++)
          aF0[i] = *(const bf16x8*)((const char*)lds + sA * 16384
                     + (i * 16 + fr) * 128 + ((kg ^ (fr & 7)) * 16));
      }
      if (p == 1){
        #pragma unroll
        for (int i = 0; i < 8; i++)
          aF1[i] = *(const bf16x8*)((const char*)lds + sA * 16384
                     + (i * 16 + fr) * 128 + (((kg + 4) ^ (fr & 7)) * 16));
      }
      bf16x8 bF[2];
      {
        const int sB = (nh == 0) ? sB0 : sB1;
        #pragma unroll
        for (int j = 0; j < 2; j++)
          bF[j] = *(const bf16x8*)((const char*)lds + sB * 16384
                     + (wc * 32 + j * 16 + fr) * 128 + ((ks ^ (fr & 7)) * 16));
      }
      stage(4 * kt + p + 7, ss);
      ss++; if (ss == 9) ss = 0;
      if (p == 3){
        if (kt < NT - 2)       asm volatile("s_waitcnt vmcnt(6)" ::: "memory");
        else if (kt == NT - 2) asm volatile("s_waitcnt vmcnt(0)" ::: "memory");
      }
      __builtin_amdgcn_s_barrier();
      __builtin_amdgcn_s_setprio(1);
      if (kb == 0){
        #pragma unroll
        for (int i = 0; i < 8; i++)
          #pragma unroll
          for (int j = 0; j < 2; j++)
            acc[i][nh][j] = __builtin_amdgcn_mfma_f32_16x16x32_bf16(aF0[i], bF[j], acc[i][nh][j], 0, 0, 0);
      } else {
        #pragma unroll
        for (int i = 0; i < 8; i++)
          #pragma unroll
          for (int j = 0; j < 2; j++)
            acc[i][nh][j] = __builtin_amdgcn_mfma_f32_16x16x32_bf16(aF1[i], bF[j], acc[i][nh][j], 0, 0, 0);
      }
      __builtin_amdgcn_s_setprio(0);
      __builtin_amdgcn_s_barrier();
    }
    rb += 4; if (rb >= 9) rb -= 9;
  }

  // epilogue: frag j=0 is u (cols 32c+0..15), j=1 is g (cols 32c+16..31)
  #pragma unroll
  for (int i = 0; i < 8; i++){
    #pragma unroll
    for (int nh = 0; nh < 2; nh++){
      const int pc = n0 + nh * 128 + wc * 32;
      const int lc = ((pc >> 5) << 4) + fr;
      #pragma unroll
      for (int r = 0; r < 4; r++){
        const int gm = m0 + wr * 128 + i * 16 + kg * 4 + r;
        float u = acc[i][nh][0][r] + bias[lc];
        float g = acc[i][nh][1][r] + bias[1024 + lc];
        float sg = g / (1.0f + expf(-g));
        obuf[(size_t)gm * 1024 + lc] = f2b(u * sg);
      }
    }
  }
}

// ================= residual GEMM + fused LayerNorm, BM=64 x BN=512 =================
// 8 waves (1M x 8N, wave 64x64), BK=64, double-buffered 72KB tiles (144 KiB LDS).
// Staging for tile kt+2 issues AFTER the kb1 barrier (its buffer provably consumed),
// so the kb1 vmcnt(0) waits on loads issued a full K-tile earlier (~0 stall).
template<int K>
__global__ __launch_bounds__(512, 2) void res8p(
    const short* __restrict__ A, const short* __restrict__ B,
    const float* __restrict__ bias,
    const float* __restrict__ sc, const float* __restrict__ bi,
    float* __restrict__ xbuf, short* __restrict__ nbuf)
{
  constexpr int NT = K / 64;          // 16
  __shared__ short lds[18 * 4096];    // 147456 B

  int bid = blockIdx.x;
  const int nwg = gridDim.x;
  bid = (bid & 7) * (nwg >> 3) + (bid >> 3);
  const int m0 = bid * 64;

  const int tid = threadIdx.x, lane = tid & 63, wid = tid >> 6;
  const int fr = lane & 15, kg = lane >> 4;

  f32x4 acc[4][4];
  const f32x4 zero = {0.f, 0.f, 0.f, 0.f};
  #pragma unroll
  for (int i = 0; i < 4; i++)
    #pragma unroll
    for (int j = 0; j < 4; j++) acc[i][j] = zero;

  const int rl0 = tid >> 3;                       // 0..63
  const int swz = ((tid & 7) ^ (rl0 & 7)) * 8;
  const short* Ab = A + ((size_t)m0 + rl0) * K + swz;
  const short* Bb = B + (size_t)rl0 * K + swz;

  auto stageT = [&](int t){
    if (t < NT){
      short* wb = lds + (t & 1) * 36864 + wid * 512;
      gl_lds16(Ab + t * 64, wb);
      #pragma unroll
      for (int u = 0; u < 8; u++)
        gl_lds16(Bb + (size_t)(u * 64) * K + t * 64, wb + (1 + u) * 4096);
    }
  };

  stageT(0);
  asm volatile("s_waitcnt vmcnt(0)" ::: "memory");
  __builtin_amdgcn_s_barrier();
  stageT(1);

  for (int kt = 0; kt < NT; ++kt){
    const char* buf = (const char*)lds + (kt & 1) * 73728;
    // ---- kb0 ----
    {
      bf16x8 aF[4], bF[4];
      #pragma unroll
      for (int i = 0; i < 4; i++){
        const int row = i * 16 + fr;
        aF[i] = *(const bf16x8*)(buf + row * 128 + ((kg ^ (row & 7)) * 16));
      }
      #pragma unroll
      for (int j = 0; j < 4; j++){
        const int row = j * 16 + fr;
        bF[j] = *(const bf16x8*)(buf + (1 + wid) * 8192 + row * 128 + ((kg ^ (row & 7)) * 16));
      }
      __builtin_amdgcn_s_barrier();
      __builtin_amdgcn_s_setprio(1);
      #pragma unroll
      for (int i = 0; i < 4; i++)
        #pragma unroll
        for (int j = 0; j < 4; j++)
          acc[i][j] = __builtin_amdgcn_mfma_f32_16x16x32_bf16(aF[i], bF[j], acc[i][j], 0, 0, 0);
      __builtin_amdgcn_s_setprio(0);
      __builtin_amdgcn_s_barrier();
    }
    // ---- kb1 ----
    {
      const int ks = kg + 4;
      bf16x8 aF[4], bF[4];
      #pragma unroll
      for (int i = 0; i < 4; i++){
        const int row = i * 16 + fr;
        aF[i] = *(const bf16x8*)(buf + row * 128 + ((ks ^ (row & 7)) * 16));
      }
      #pragma unroll
      for (int j = 0; j < 4; j++){
        const int row = j * 16 + fr;
        bF[j] = *(const bf16x8*)(buf + (1 + wid) * 8192 + row * 128 + ((ks ^ (row & 7)) * 16));
      }
      if (kt < NT - 1) asm volatile("s_waitcnt vmcnt(0)" ::: "memory");  // tile kt+1 landed
      __builtin_amdgcn_s_barrier();
      stageT(kt + 2);   // overwrites buf[kt&1]; all its reads completed before this barrier
      __builtin_amdgcn_s_setprio(1);
      #pragma unroll
      for (int i = 0; i < 4; i++)
        #pragma unroll
        for (int j = 0; j < 4; j++)
          acc[i][j] = __builtin_amdgcn_mfma_f32_16x16x32_bf16(aF[i], bF[j], acc[i][j], 0, 0, 0);
      __builtin_amdgcn_s_setprio(0);
      __builtin_amdgcn_s_barrier();
    }
  }

  // ---- epilogue: residual + decay (in-place in acc) ----
  #pragma unroll
  for (int i = 0; i < 4; i++){
    #pragma unroll
    for (int r = 0; r < 4; r++){
      const int row = i * 16 + kg * 4 + r;
      const int gm = m0 + row;
      const float d = ((((gm & (SEQ-1)) + 1) % 10) == 0) ? 0.1f : 1.0f;
      #pragma unroll
      for (int j = 0; j < 4; j++){
        const int gn = wid * 64 + j * 16 + fr;
        const float xo = xbuf[(size_t)gm * 512 + gn];
        acc[i][j][r] = (xo + acc[i][j][r] + bias[gn]) * d;
      }
    }
  }
  // ---- fused LayerNorm over the full 512-wide row ----
  float* fs = (float*)lds;
  __syncthreads();   // drain in-flight ds_reads before reusing staging LDS as scratch
  #pragma unroll
  for (int i = 0; i < 4; i++){
    #pragma unroll
    for (int r = 0; r < 4; r++){
      float s = acc[i][0][r] + acc[i][1][r] + acc[i][2][r] + acc[i][3][r];
      float q = acc[i][0][r]*acc[i][0][r] + acc[i][1][r]*acc[i][1][r]
              + acc[i][2][r]*acc[i][2][r] + acc[i][3][r]*acc[i][3][r];
      #pragma unroll
      for (int o = 1; o < 16; o <<= 1){ s += __shfl_xor(s, o); q += __shfl_xor(q, o); }
      if (fr == 0){
        const int row = i * 16 + kg * 4 + r;
        fs[wid * 64 + row]       = s;
        fs[512 + wid * 64 + row] = q;
      }
    }
  }
  __syncthreads();
  if (tid < 64){
    float s = 0.f, q = 0.f;
    #pragma unroll
    for (int w8 = 0; w8 < 8; w8++){ s += fs[w8 * 64 + tid]; q += fs[512 + w8 * 64 + tid]; }
    const float mu = s * (1.0f / 512.0f);
    const float var = q * (1.0f / 512.0f) - mu * mu;
    fs[1024 + tid] = mu;
    fs[1088 + tid] = rsqrtf(var + 1e-5f);
  }
  __syncthreads();
  #pragma unroll
  for (int i = 0; i < 4; i++){
    #pragma unroll
    for (int r = 0; r < 4; r++){
      const int row = i * 16 + kg * 4 + r;
      const int gm = m0 + row;
      const float mu = fs[1024 + row], rs = fs[1088 + row];
      #pragma unroll
      for (int j = 0; j < 4; j++){
        const int gn = wid * 64 + j * 16 + fr;
        const float v = acc[i][j][r];
        xbuf[(size_t)gm * 512 + gn] = v;
        nbuf[(size_t)gm * 512 + gn] = f2b((v - mu) * rs * sc[gn] + bi[gn]);
      }
    }
  }
}

// ================= input projection + pos_emb + fused LN0, BM=64 x BN=512, K=128 =================
__global__ __launch_bounds__(512, 2) void in0ln(
    const short* __restrict__ A, const short* __restrict__ B,
    const float* __restrict__ bias, const float* __restrict__ pos,
    const float* __restrict__ sc, const float* __restrict__ bi,
    float* __restrict__ xbuf, short* __restrict__ nbuf)
{
  constexpr int K = 128;
  __shared__ short lds[18 * 4096];

  int bid = blockIdx.x;
  const int nwg = gridDim.x;
  bid = (bid & 7) * (nwg >> 3) + (bid >> 3);
  const int m0 = bid * 64;

  const int tid = threadIdx.x, lane = tid & 63, wid = tid >> 6;
  const int fr = lane & 15, kg = lane >> 4;

  f32x4 acc[4][4];
  const f32x4 zero = {0.f, 0.f, 0.f, 0.f};
  #pragma unroll
  for (int i = 0; i < 4; i++)
    #pragma unroll
    for (int j = 0; j < 4; j++) acc[i][j] = zero;

  const int rl0 = tid >> 3;
  const int swz = ((tid & 7) ^ (rl0 & 7)) * 8;
  const short* Ab = A + ((size_t)m0 + rl0) * K + swz;
  const short* Bb = B + (size_t)rl0 * K + swz;

  #pragma unroll
  for (int t = 0; t < 2; t++){
    short* wb = lds + t * 36864 + wid * 512;
    gl_lds16(Ab + t * 64, wb);
    #pragma unroll
    for (int u = 0; u < 8; u++)
      gl_lds16(Bb + (size_t)(u * 64) * K + t * 64, wb + (1 + u) * 4096);
  }
  asm volatile("s_waitcnt vmcnt(0)" ::: "memory");
  __builtin_amdgcn_s_barrier();

  #pragma unroll
  for (int kt = 0; kt < 2; ++kt){
    const char* buf = (const char*)lds + kt * 73728;
    #pragma unroll
    for (int kb = 0; kb < 2; kb++){
      const int ks = kg + kb * 4;
      bf16x8 aF[4], bF[4];
      #pragma unroll
      for (int i = 0; i < 4; i++){
        const int row = i * 16 + fr;
        aF[i] = *(const bf16x8*)(buf + row * 128 + ((ks ^ (row & 7)) * 16));
      }
      #pragma unroll
      for (int j = 0; j < 4; j++){
        const int row = j * 16 + fr;
        bF[j] = *(const bf16x8*)(buf + (1 + wid) * 8192 + row * 128 + ((ks ^ (row & 7)) * 16));
      }
      #pragma unroll
      for (int i = 0; i < 4; i++)
        #pragma unroll
        for (int j = 0; j < 4; j++)
          acc[i][j] = __builtin_amdgcn_mfma_f32_16x16x32_bf16(aF[i], bF[j], acc[i][j], 0, 0, 0);
    }
  }

  // epilogue: + bias + pos_emb, then fused LN (ln_scale[0]/ln_bias[0])
  #pragma unroll
  for (int i = 0; i < 4; i++){
    #pragma unroll
    for (int r = 0; r < 4; r++){
      const int row = i * 16 + kg * 4 + r;
      const int gm = m0 + row;
      #pragma unroll
      for (int j = 0; j < 4; j++){
        const int gn = wid * 64 + j * 16 + fr;
        acc[i][j][r] += bias[gn] + pos[(size_t)(gm & (SEQ-1)) * 512 + gn];
      }
    }
  }
  float* fs = (float*)lds;
  __syncthreads();
  #pragma unroll
  for (int i = 0; i < 4; i++){
    #pragma unroll
    for (int r = 0; r < 4; r++){
      float s = acc[i][0][r] + acc[i][1][r] + acc[i][2][r] + acc[i][3][r];
      float q = acc[i][0][r]*acc[i][0][r] + acc[i][1][r]*acc[i][1][r]
              + acc[i][2][r]*acc[i][2][r] + acc[i][3][r]*acc[i][3][r];
      #pragma unroll
      for (int o = 1; o < 16; o <<= 1){ s += __shfl_xor(s, o); q += __shfl_xor(q, o); }
      if (fr == 0){
        const int row = i * 16 + kg * 4 + r;
        fs[wid * 64 + row]       = s;
        fs[512 + wid * 64 + row] = q;
      }
    }
  }
  __syncthreads();
  if (tid < 64){
    float s = 0.f, q = 0.f;
    #pragma unroll
    for (int w8 = 0; w8 < 8; w8++){ s += fs[w8 * 64 + tid]; q += fs[512 + w8 * 64 + tid]; }
    const float mu = s * (1.0f / 512.0f);
    const float var = q * (1.0f / 512.0f) - mu * mu;
    fs[1024 + tid] = mu;
    fs[1088 + tid] = rsqrtf(var + 1e-5f);
  }
  __syncthreads();
  #pragma unroll
  for (int i = 0; i < 4; i++){
    #pragma unroll
    for (int r = 0; r < 4; r++){
      const int row = i * 16 + kg * 4 + r;
      const int gm = m0 + row;
      const float mu = fs[1024 + row], rs = fs[1088 + row];
      #pragma unroll
      for (int j = 0; j < 4; j++){
        const int gn = wid * 64 + j * 16 + fr;
        const float v = acc[i][j][r];
        xbuf[(size_t)gm * 512 + gn] = v;
        nbuf[(size_t)gm * 512 + gn] = f2b((v - mu) * rs * sc[gn] + bi[gn]);
      }
    }
  }
}

// ================= merged heads GEMM (128x128, K=512), masked =================
__global__ __launch_bounds__(256) void heads_k(
    const short* __restrict__ A, const short* __restrict__ B,
    const float* __restrict__ bias0, const float* __restrict__ bias1,
    float* __restrict__ fout, const void* __restrict__ mask, const int* __restrict__ flagp)
{
  constexpr int K = 512, BM = 128, BN = 128;
  __shared__ short lds[(BM + BN) * 64];
  short* lA = lds;
  short* lB = lds + BM * 64;

  const int nbx = gridDim.x;
  int bid = blockIdx.y * nbx + blockIdx.x;
  const int nwg = nbx * gridDim.y;
  bid = (bid & 7) * (nwg >> 3) + (bid >> 3);
  const int n0 = (bid % nbx) * BN, m0 = (bid / nbx) * BM;

  const int tid = threadIdx.x, lane = tid & 63, wid = tid >> 6;
  const int lr  = lane >> 3;
  const int lks = (lane & 7) ^ (lr & 7);
  const int fr = lane & 15;
  const int kg = lane >> 4;

  const int wr = wid >> 1, wc = wid & 1;
  const int rA0 = wr * 64 + fr;
  const int rB0 = wc * 64 + fr;

  f32x4 acc[4][4];
  const f32x4 zero = {0.f, 0.f, 0.f, 0.f};
  #pragma unroll
  for (int i = 0; i < 4; i++)
    #pragma unroll
    for (int j = 0; j < 4; j++) acc[i][j] = zero;

  const short* Ab = A + (size_t)m0 * K + (size_t)lr * K + lks * 8;
  const short* Bb = B + (size_t)n0 * K + (size_t)lr * K + lks * 8;

  for (int kt = 0; kt < K; kt += 64){
    __syncthreads();
    #pragma unroll
    for (int c = 0; c < 4; c++)
      gl_lds16(Ab + kt + (size_t)(wid + c * 4) * 8 * K, lA + (wid + c * 4) * 512);
    #pragma unroll
    for (int c = 0; c < 4; c++)
      gl_lds16(Bb + kt + (size_t)(wid + c * 4) * 8 * K, lB + (wid + c * 4) * 512);
    __syncthreads();

    #pragma unroll
    for (int kb8 = 0; kb8 < 8; kb8 += 4){
      bf16x8 aF[4], bF[4];
      #pragma unroll
      for (int i = 0; i < 4; i++){
        const int row = rA0 + i * 16;
        aF[i] = *(const bf16x8*)((const char*)lA + row * 128 + (((kg + kb8) ^ (row & 7)) * 16));
      }
      #pragma unroll
      for (int j = 0; j < 4; j++){
        const int row = rB0 + j * 16;
        bF[j] = *(const bf16x8*)((const char*)lB + row * 128 + (((kg + kb8) ^ (row & 7)) * 16));
      }
      #pragma unroll
      for (int i = 0; i < 4; i++)
        #pragma unroll
        for (int j = 0; j < 4; j++)
          acc[i][j] = __builtin_amdgcn_mfma_f32_16x16x32_bf16(aF[i], bF[j], acc[i][j], 0, 0, 0);
    }
  }

  const int col0 = n0 + wc * 64 + fr;
  const int row0 = m0 + wr * 64 + kg * 4;
  const int flag = *flagp;

  #pragma unroll
  for (int i = 0; i < 4; i++){
    #pragma unroll
    for (int r = 0; r < 4; r++){
      const int gm = row0 + i * 16 + r;
      const bool mk = mask_at(mask, flag, gm);
      #pragma unroll
      for (int j = 0; j < 4; j++){
        const int gn = col0 + j * 16;
        const float v = acc[i][j][r];
        if (gn < 128){
          fout[(size_t)gm * 128 + gn] = mk ? (v + bias0[gn]) : 0.0f;
        } else {
          const int gs = gn - 128;
          fout[(size_t)16384 * 128 + (size_t)gm * 256 + gs] = mk ? (v + bias1[gs]) : 0.0f;
        }
      }
    }
  }
}

extern "C" void kernel_launch(void* const* d_in, const int* in_sizes, int n_in,
                              void* d_out, int out_size, void* d_ws, size_t ws_size,
                              hipStream_t stream){
  const float* frames    = (const float*)d_in[0];
  const void*  mask      = d_in[1];
  const float* W_in_proj = (const float*)d_in[2];
  const float* b_in_proj = (const float*)d_in[3];
  const float* pos_emb   = (const float*)d_in[4];
  const float* ln_scale  = (const float*)d_in[5];
  const float* ln_bias   = (const float*)d_in[6];
  const float* W_in      = (const float*)d_in[7];
  const float* b_in      = (const float*)d_in[8];
  const float* W_out     = (const float*)d_in[9];
  const float* b_out     = (const float*)d_in[10];
  const float* fn_scale  = (const float*)d_in[11];
  const float* fn_bias   = (const float*)d_in[12];
  const float* W_frame   = (const float*)d_in[13];
  const float* b_frame   = (const float*)d_in[14];
  const float* W_sym     = (const float*)d_in[15];
  const float* b_sym     = (const float*)d_in[16];

  char* w = (char*)d_ws;
  int*   flag = (int*)w;
  float* xbuf = (float*)(w + 256);                                    // 16384*512 f32
  short* nbuf = (short*)(w + 256 + 33554432);                         // 16384*512 bf16
  short* abuf = (short*)(w + 256 + 33554432 + 16777216);              // 16384*1024 bf16
  short* frb  = (short*)(w + 256 + 33554432 + 16777216 + 33554432);   // 16384*128 bf16
  short* Wt0  = frb + (size_t)16384 * 128;   // [512][128]
  short* Wt1  = Wt0 + (size_t)512 * 128;     // 4x [2048][512] (u/g interleaved)
  short* Wt2  = Wt1 + (size_t)4 * 2048 * 512;// 4x [512][1024]
  short* Wt3  = Wt2 + (size_t)4 * 512 * 1024;// [128][512]
  short* Wt4  = Wt3 + (size_t)128 * 512;     // [256][512]

  prep<<<8449, 256, 0, stream>>>(frames, frb, W_in_proj, Wt0, W_in, Wt1, W_out, Wt2,
                                 W_frame, Wt3, W_sym, Wt4, (const unsigned char*)mask, flag);

  in0ln<<<256, 512, 0, stream>>>(frb, Wt0, b_in_proj, pos_emb, ln_scale, ln_bias, xbuf, nbuf);

  for (int l = 0; l < 4; l++){
    glu8p<512><<<dim3(8, 64), 512, 0, stream>>>(nbuf,
        Wt1 + (size_t)l * 2048 * 512, b_in + l * 2048, abuf);
    const float* s2 = (l < 3) ? (ln_scale + (l + 1) * 512) : fn_scale;
    const float* b2 = (l < 3) ? (ln_bias  + (l + 1) * 512) : fn_bias;
    res8p<1024><<<256, 512, 0, stream>>>(abuf, Wt2 + (size_t)l * 512 * 1024,
        b_out + l * 512, s2, b2, xbuf, nbuf);
  }

  heads_k<<<dim3(3, 128), 256, 0, stream>>>(nbuf, Wt3, b_frame, b_sym,
      (float*)d_out, mask, flag);
}